// Round 1
// 1153.011 us; speedup vs baseline: 1.2781x; 1.2781x over previous
//
#include <hip/hip_runtime.h>
#include <cstdint>
#include <cstddef>

// ---------------------------------------------------------------------------
// NoiseBlockMoE (B=4,T=1024,D=1024,H=16,E=8,top2,FF=4096)
// Round 4: attention moved to MFMA (bf16 split-2, 3 sweeps) flash kernel.
// QK^T computed swapped (S^T = K·Q^T) so Q lives in registers and softmax
// reduction is 2 shuffles; PV computed as O^T = V^T·P^T with V stored
// transposed at staging time. Rest unchanged from round 3.
// ---------------------------------------------------------------------------

#define AS1 __attribute__((address_space(1)))
#define AS3 __attribute__((address_space(3)))

typedef unsigned short u16;
typedef __attribute__((ext_vector_type(8))) short short8;   // 8 bf16 = 4 VGPR
typedef __attribute__((ext_vector_type(4))) float f32x4;

constexpr int Bc = 4, Tc = 1024, Dc = 1024, Hc = 16, Ec = 8, FFc = 4096;
constexpr int Mtok = Bc * Tc;   // 4096 tokens

// plane strides (elements)
constexpr size_t PS_WQKV = (size_t)3 * Dc * Dc;   // 3145728
constexpr size_t PS_WPROJ = (size_t)Dc * Dc;      // 1048576
constexpr size_t PS_H = (size_t)Mtok * Dc;        // 4194304

__device__ __forceinline__ u16 f2bf(float f) {              // RNE f32->bf16
  unsigned u = __float_as_uint(f);
  u += 0x7fffu + ((u >> 16) & 1u);
  return (u16)(u >> 16);
}
__device__ __forceinline__ float bf2f(u16 v) { return __uint_as_float(((unsigned)v) << 16); }
__device__ __forceinline__ float gelu_f(float v) {          // exact GELU (erf)
  return 0.5f * v * (1.0f + erff(v * 0.70710678118654752440f));
}

// ---------------------------------------------------------------- cvt f32->bf16 (plain)
__global__ __launch_bounds__(256) void cvt_bf16_kernel(const float* __restrict__ in,
                                                       u16* __restrict__ out, int n4) {
  int i = blockIdx.x * 256 + threadIdx.x;
  if (i >= n4) return;
  float4 v = reinterpret_cast<const float4*>(in)[i];
  uint2 o;
  o.x = (unsigned)f2bf(v.x) | ((unsigned)f2bf(v.y) << 16);
  o.y = (unsigned)f2bf(v.z) | ((unsigned)f2bf(v.w) << 16);
  reinterpret_cast<uint2*>(out)[i] = o;
}

// ---------------------------------------------------------------- fp32 -> 3 bf16 planes
__global__ __launch_bounds__(256) void split3_kernel(const float* __restrict__ in,
                                                     u16* __restrict__ out,
                                                     size_t ps, int n4) {
  int i = blockIdx.x * 256 + threadIdx.x;
  if (i >= n4) return;
  float4 v = reinterpret_cast<const float4*>(in)[i];
  float a[4] = {v.x, v.y, v.z, v.w};
  unsigned h[4], md[4], lo[4];
#pragma unroll
  for (int j = 0; j < 4; ++j) {
    u16 hh = f2bf(a[j]); float r = a[j] - bf2f(hh);
    u16 mm = f2bf(r);    float r2 = r - bf2f(mm);
    u16 ll = f2bf(r2);
    h[j] = hh; md[j] = mm; lo[j] = ll;
  }
  uint2 o0, o1, o2;
  o0.x = h[0] | (h[1] << 16);  o0.y = h[2] | (h[3] << 16);
  o1.x = md[0] | (md[1] << 16); o1.y = md[2] | (md[3] << 16);
  o2.x = lo[0] | (lo[1] << 16); o2.y = lo[2] | (lo[3] << 16);
  const size_t base = (size_t)i * 4;
  *(uint2*)&out[base] = o0;
  *(uint2*)&out[ps + base] = o1;
  *(uint2*)&out[2 * ps + base] = o2;
}

// ---------------------------------------------------------------- LN1 (+c) -> 3 bf16 planes
__global__ __launch_bounds__(256) void ln1_kernel(const float* __restrict__ x,
                                                  const float* __restrict__ w,
                                                  const float* __restrict__ c,
                                                  u16* __restrict__ hp) {
  const int row = blockIdx.x, tid = threadIdx.x;
  const int b = row >> 10;   // T=1024
  const float4 v = reinterpret_cast<const float4*>(x + (size_t)row * Dc)[tid];
  __shared__ float red[256];
  red[tid] = v.x + v.y + v.z + v.w;
  __syncthreads();
  for (int s = 128; s > 0; s >>= 1) { if (tid < s) red[tid] += red[tid + s]; __syncthreads(); }
  const float mu = red[0] * (1.0f / Dc);
  __syncthreads();
  const float dx = v.x - mu, dy = v.y - mu, dz = v.z - mu, dw = v.w - mu;
  red[tid] = dx * dx + dy * dy + dz * dz + dw * dw;
  __syncthreads();
  for (int s = 128; s > 0; s >>= 1) { if (tid < s) red[tid] += red[tid + s]; __syncthreads(); }
  const float rs = rsqrtf(red[0] * (1.0f / Dc) + 1e-5f);
  const float4 wv = reinterpret_cast<const float4*>(w)[tid];
  const float4 cv = reinterpret_cast<const float4*>(c + (size_t)b * Dc)[tid];
  float a[4];
  a[0] = dx * rs * wv.x + cv.x; a[1] = dy * rs * wv.y + cv.y;
  a[2] = dz * rs * wv.z + cv.z; a[3] = dw * rs * wv.w + cv.w;
  unsigned h[4], md[4], lo[4];
#pragma unroll
  for (int j = 0; j < 4; ++j) {
    u16 hh = f2bf(a[j]); float r = a[j] - bf2f(hh);
    u16 mm = f2bf(r);    float r2 = r - bf2f(mm);
    u16 ll = f2bf(r2);
    h[j] = hh; md[j] = mm; lo[j] = ll;
  }
  uint2 o0, o1, o2;
  o0.x = h[0] | (h[1] << 16);  o0.y = h[2] | (h[3] << 16);
  o1.x = md[0] | (md[1] << 16); o1.y = md[2] | (md[3] << 16);
  o2.x = lo[0] | (lo[1] << 16); o2.y = lo[2] | (lo[3] << 16);
  const size_t base = (size_t)row * Dc + tid * 4;
  *(uint2*)&hp[base] = o0;
  *(uint2*)&hp[PS_H + base] = o1;
  *(uint2*)&hp[2 * PS_H + base] = o2;
}

// ---------------------------------------------------------------- LN2 -> f32 (d_out) + bf16
__global__ __launch_bounds__(256) void ln2_kernel(const float* __restrict__ xin,
                                                  const float* __restrict__ w,
                                                  float* __restrict__ xf,
                                                  u16* __restrict__ xb) {
  const int row = blockIdx.x, tid = threadIdx.x;
  const float4 v = reinterpret_cast<const float4*>(xin + (size_t)row * Dc)[tid];
  __shared__ float red[256];
  red[tid] = v.x + v.y + v.z + v.w;
  __syncthreads();
  for (int s = 128; s > 0; s >>= 1) { if (tid < s) red[tid] += red[tid + s]; __syncthreads(); }
  const float mu = red[0] * (1.0f / Dc);
  __syncthreads();
  const float dx = v.x - mu, dy = v.y - mu, dz = v.z - mu, dw = v.w - mu;
  red[tid] = dx * dx + dy * dy + dz * dz + dw * dw;
  __syncthreads();
  for (int s = 128; s > 0; s >>= 1) { if (tid < s) red[tid] += red[tid + s]; __syncthreads(); }
  const float rs = rsqrtf(red[0] * (1.0f / Dc) + 1e-5f);
  const float4 wv = reinterpret_cast<const float4*>(w)[tid];
  float4 ov;
  ov.x = dx * rs * wv.x; ov.y = dy * rs * wv.y; ov.z = dz * rs * wv.z; ov.w = dw * rs * wv.w;
  reinterpret_cast<float4*>(xf + (size_t)row * Dc)[tid] = ov;
  uint2 o;
  o.x = (unsigned)f2bf(ov.x) | ((unsigned)f2bf(ov.y) << 16);
  o.y = (unsigned)f2bf(ov.z) | ((unsigned)f2bf(ov.w) << 16);
  reinterpret_cast<uint2*>(xb + (size_t)row * Dc)[tid] = o;
}

// ---------------------------------------------------------------- MFMA GEMM core (single, bf16)
__device__ __forceinline__ void gemm_mfma_core(const u16* a0, const u16* a1,
                                               const u16* b0, const u16* b1,
                                               int K, u16* As, u16* Bs, f32x4 acc[4][4]) {
  const int tid = threadIdx.x;
  const int lane = tid & 63;
  const int wave = tid >> 6;
  const int wm = (wave & 1) * 64;
  const int wn = (wave >> 1) * 64;
  const int frow = lane & 15;
  const int fk = (lane >> 4) * 8;
  int aoff[4], boff[4];
#pragma unroll
  for (int t = 0; t < 4; ++t) {
    aoff[t] = (wm + t * 16 + frow) * 32 + fk;
    boff[t] = (wn + t * 16 + frow) * 32 + fk;
  }
  const int lds0 = tid * 8;
  for (int k0 = 0; k0 < K; k0 += 32) {
    __builtin_amdgcn_global_load_lds((AS1 void*)a0, (AS3 void*)(As + lds0), 16, 0, 0);
    __builtin_amdgcn_global_load_lds((AS1 void*)a1, (AS3 void*)(As + 2048 + lds0), 16, 0, 0);
    __builtin_amdgcn_global_load_lds((AS1 void*)b0, (AS3 void*)(Bs + lds0), 16, 0, 0);
    __builtin_amdgcn_global_load_lds((AS1 void*)b1, (AS3 void*)(Bs + 2048 + lds0), 16, 0, 0);
    a0 += 32; a1 += 32; b0 += 32; b1 += 32;
    __syncthreads();
    short8 af[4], bfr[4];
#pragma unroll
    for (int t = 0; t < 4; ++t) af[t] = *(const short8*)(As + aoff[t]);
#pragma unroll
    for (int t = 0; t < 4; ++t) bfr[t] = *(const short8*)(Bs + boff[t]);
#pragma unroll
    for (int mt = 0; mt < 4; ++mt)
#pragma unroll
      for (int nt = 0; nt < 4; ++nt)
        acc[mt][nt] = __builtin_amdgcn_mfma_f32_16x16x32_bf16(af[mt], bfr[nt], acc[mt][nt], 0, 0, 0);
    __syncthreads();
  }
}

// ---------------------------------------------------------------- split-3 GEMM core: 6 plane-pair sweeps
__device__ __forceinline__ void gemm_split_core(const u16* A0, const u16* A1, size_t Aps,
                                                const u16* B0, const u16* B1, size_t Bps,
                                                int K, u16* As, u16* Bs, f32x4 acc[4][4]) {
  const int PA[6] = {0, 0, 1, 1, 0, 2};
  const int PB[6] = {0, 1, 0, 1, 2, 0};
  for (int t6 = 0; t6 < 6; ++t6) {
    gemm_mfma_core(A0 + PA[t6] * Aps, A1 + PA[t6] * Aps,
                   B0 + PB[t6] * Bps, B1 + PB[t6] * Bps, K, As, Bs, acc);
  }
}

// ---------------------------------------------------------------- qkv split GEMM -> fp32
__global__ __launch_bounds__(256) void gemm_qkv_kernel(const u16* __restrict__ A,
                                                       const u16* __restrict__ Bw,
                                                       float* __restrict__ Cout) {
  __shared__ u16 As[128 * 32], Bs[128 * 32];
  const int bn = blockIdx.x, bm = blockIdx.y, tid = threadIdx.x;
  const int r = tid >> 2, kk = (tid & 3) * 8;
  const u16* a0 = A + (size_t)(bm * 128 + r) * 1024 + kk;
  const u16* a1 = a0 + (size_t)64 * 1024;
  const u16* b0 = Bw + (size_t)(bn * 128 + r) * 1024 + kk;
  const u16* b1 = b0 + (size_t)64 * 1024;
  f32x4 acc[4][4] = {};
  gemm_split_core(a0, a1, PS_H, b0, b1, PS_WQKV, 1024, As, Bs, acc);
  const int lane = tid & 63, wave = tid >> 6;
  const int wm = (wave & 1) * 64, wn = (wave >> 1) * 64;
  const int col = lane & 15, rb = (lane >> 4) * 4;
#pragma unroll
  for (int mt = 0; mt < 4; ++mt)
#pragma unroll
    for (int rr = 0; rr < 4; ++rr) {
      const int m = bm * 128 + wm + mt * 16 + rb + rr;
#pragma unroll
      for (int nt = 0; nt < 4; ++nt) {
        const int n = bn * 128 + wn + nt * 16 + col;
        Cout[(size_t)m * 3072 + n] = acc[mt][nt][rr];
      }
    }
}

// ---------------------------------------------------------------- proj split GEMM + residual -> fp32
__global__ __launch_bounds__(256) void gemm_proj_kernel(const u16* __restrict__ A,
                                                        const u16* __restrict__ Bw,
                                                        const float* __restrict__ xres,
                                                        float* __restrict__ xmid) {
  __shared__ u16 As[128 * 32], Bs[128 * 32];
  const int bn = blockIdx.x, bm = blockIdx.y, tid = threadIdx.x;
  const int r = tid >> 2, kk = (tid & 3) * 8;
  const u16* a0 = A + (size_t)(bm * 128 + r) * 1024 + kk;
  const u16* a1 = a0 + (size_t)64 * 1024;
  const u16* b0 = Bw + (size_t)(bn * 128 + r) * 1024 + kk;
  const u16* b1 = b0 + (size_t)64 * 1024;
  f32x4 acc[4][4] = {};
  gemm_split_core(a0, a1, PS_H, b0, b1, PS_WPROJ, 1024, As, Bs, acc);
  const int lane = tid & 63, wave = tid >> 6;
  const int wm = (wave & 1) * 64, wn = (wave >> 1) * 64;
  const int col = lane & 15, rb = (lane >> 4) * 4;
#pragma unroll
  for (int mt = 0; mt < 4; ++mt)
#pragma unroll
    for (int rr = 0; rr < 4; ++rr) {
      const int m = bm * 128 + wm + mt * 16 + rb + rr;
#pragma unroll
      for (int nt = 0; nt < 4; ++nt) {
        const int n = bn * 128 + wn + nt * 16 + col;
        xmid[(size_t)m * 1024 + n] = xres[(size_t)m * 1024 + n] + acc[mt][nt][rr];
      }
    }
}

// ---------------------------------------------------------------- attention, bf16 split-2 MFMA flash
// Grid (T/64, B*H). 4 waves/block; wave w owns q rows q0+16w..+15 of one (b,h).
// Swapped QK^T: S^T = K·Q^T  (A = K rows natural [k][d], B = Q in registers)
//   -> C layout col = q = lane&15, row = local k = 16*kt + 4*(lane>>4) + r.
// Softmax stats per q-column: register reduce + shfl_xor(16/32).
// PV: O^T = V^T · P^T  (A = V transposed-at-stage [d][k], B = P from LDS [q][k]).
// Split-2 bf16 (hi+lo, 3 sweeps, lo·lo dropped): rel err ~8e-6 ≈ fp32 for this use.
__global__ __launch_bounds__(256, 3) void attn_mfma_kernel(const float* __restrict__ qkv,
                                                           float* __restrict__ obuf) {
  constexpr int KS = 72;    // K/V row stride (u16): 144B rows -> 16B-aligned b128 reads
  constexpr int PSt = 68;   // P row stride (u16): 136B rows -> 8B-aligned b64 writes
  __shared__ u16 Kh[64 * KS], Klo[64 * KS];
  __shared__ u16 Vh[64 * KS], Vlo[64 * KS];
  __shared__ u16 Ph[4][16 * PSt], Pl[4][16 * PSt];

  const int tid = threadIdx.x, lane = tid & 63, w = tid >> 6;
  const int lr = lane & 15, g = lane >> 4;
  const int bh = blockIdx.y, b = bh >> 4, h = bh & 15;
  const int blk = blockIdx.x;                 // q-block of 64 rows; also #chunks-1
  const int qrow = blk * 64 + w * 16 + lr;    // this lane's q (C-layout column)

  // ---- Q fragments in registers (B operand: n=lr, k=8g+j, ksteps s=0,1), ×1/8 exact
  short8 qh[2], ql[2];
  {
    const float* qp = qkv + (size_t)(b * Tc + qrow) * 3072 + h * 64 + g * 8;
    const float4 f0 = *(const float4*)(qp);
    const float4 f1 = *(const float4*)(qp + 4);
    const float4 f2 = *(const float4*)(qp + 32);
    const float4 f3 = *(const float4*)(qp + 36);
    const float qq[16] = {f0.x, f0.y, f0.z, f0.w, f1.x, f1.y, f1.z, f1.w,
                          f2.x, f2.y, f2.z, f2.w, f3.x, f3.y, f3.z, f3.w};
#pragma unroll
    for (int s = 0; s < 2; ++s)
#pragma unroll
      for (int j = 0; j < 8; ++j) {
        const float v = qq[s * 8 + j] * 0.125f;
        const u16 hi = f2bf(v);
        qh[s][j] = (short)hi;
        ql[s][j] = (short)f2bf(v - bf2f(hi));
      }
  }

  const int tkl = (tid & 31) * 2;   // staging: local k row pair
  const int td0 = (tid >> 5) * 8;   // staging: d group
  const float* kgb = qkv + (size_t)b * Tc * 3072 + 1024 + h * 64;
  const float* vgb = kgb + 1024;

  f32x4 oacc[4] = {};               // O^T frags [dt]: col=q=lr, row=16dt+4g+r
  float mrun = -1e30f, lrun = 0.f;

  for (int c = 0; c <= blk; ++c) {
    const int k0 = c * 64;
    __syncthreads();                // prior chunk's LDS reads complete
    {
      // --- stage K (natural) and V (transposed) as bf16 hi/lo planes
      const float* kr0 = kgb + (size_t)(k0 + tkl) * 3072 + td0;
      const float* kr1 = kr0 + 3072;
      const float* vr0 = vgb + (size_t)(k0 + tkl) * 3072 + td0;
      const float* vr1 = vr0 + 3072;
      const float4 ka0 = *(const float4*)kr0, ka1 = *(const float4*)(kr0 + 4);
      const float4 kb0 = *(const float4*)kr1, kb1 = *(const float4*)(kr1 + 4);
      const float4 va0 = *(const float4*)vr0, va1 = *(const float4*)(vr0 + 4);
      const float4 vb0 = *(const float4*)vr1, vb1 = *(const float4*)(vr1 + 4);
      const float ka[8] = {ka0.x, ka0.y, ka0.z, ka0.w, ka1.x, ka1.y, ka1.z, ka1.w};
      const float kb[8] = {kb0.x, kb0.y, kb0.z, kb0.w, kb1.x, kb1.y, kb1.z, kb1.w};
      const float va[8] = {va0.x, va0.y, va0.z, va0.w, va1.x, va1.y, va1.z, va1.w};
      const float vb[8] = {vb0.x, vb0.y, vb0.z, vb0.w, vb1.x, vb1.y, vb1.z, vb1.w};
      short8 kh0, kl0, kh1, kl1;
#pragma unroll
      for (int j = 0; j < 8; ++j) {
        const u16 h0 = f2bf(ka[j]); kh0[j] = (short)h0; kl0[j] = (short)f2bf(ka[j] - bf2f(h0));
        const u16 h1 = f2bf(kb[j]); kh1[j] = (short)h1; kl1[j] = (short)f2bf(kb[j] - bf2f(h1));
      }
      *(short8*)(Kh + tkl * KS + td0) = kh0;
      *(short8*)(Kh + (tkl + 1) * KS + td0) = kh1;
      *(short8*)(Klo + tkl * KS + td0) = kl0;
      *(short8*)(Klo + (tkl + 1) * KS + td0) = kl1;
#pragma unroll
      for (int i = 0; i < 8; ++i) {                 // V^T: [d][k], k-pair packed u32
        const u16 h0 = f2bf(va[i]); const u16 l0 = f2bf(va[i] - bf2f(h0));
        const u16 h1 = f2bf(vb[i]); const u16 l1 = f2bf(vb[i] - bf2f(h1));
        *(unsigned*)(Vh + (td0 + i) * KS + tkl) = (unsigned)h0 | ((unsigned)h1 << 16);
        *(unsigned*)(Vlo + (td0 + i) * KS + tkl) = (unsigned)l0 | ((unsigned)l1 << 16);
      }
    }
    __syncthreads();

    // --- S^T = K·Q^T, split-2 (hi·hi + lo·hi + hi·lo)
    f32x4 sacc[4] = {};
#pragma unroll
    for (int kt = 0; kt < 4; ++kt) {
      const u16* kap = Kh + (kt * 16 + lr) * KS + g * 8;
      const u16* klp = Klo + (kt * 16 + lr) * KS + g * 8;
      const short8 ah0 = *(const short8*)kap;
      const short8 ah1 = *(const short8*)(kap + 32);
      const short8 al0 = *(const short8*)klp;
      const short8 al1 = *(const short8*)(klp + 32);
      sacc[kt] = __builtin_amdgcn_mfma_f32_16x16x32_bf16(ah0, qh[0], sacc[kt], 0, 0, 0);
      sacc[kt] = __builtin_amdgcn_mfma_f32_16x16x32_bf16(al0, qh[0], sacc[kt], 0, 0, 0);
      sacc[kt] = __builtin_amdgcn_mfma_f32_16x16x32_bf16(ah0, ql[0], sacc[kt], 0, 0, 0);
      sacc[kt] = __builtin_amdgcn_mfma_f32_16x16x32_bf16(ah1, qh[1], sacc[kt], 0, 0, 0);
      sacc[kt] = __builtin_amdgcn_mfma_f32_16x16x32_bf16(al1, qh[1], sacc[kt], 0, 0, 0);
      sacc[kt] = __builtin_amdgcn_mfma_f32_16x16x32_bf16(ah1, ql[1], sacc[kt], 0, 0, 0);
    }

    // --- causal mask (diagonal chunk only; wave-uniform branch)
    if (c == blk) {
#pragma unroll
      for (int kt = 0; kt < 4; ++kt)
#pragma unroll
        for (int r = 0; r < 4; ++r)
          if (k0 + kt * 16 + g * 4 + r > qrow) sacc[kt][r] = -1e30f;
    }

    // --- online softmax (stats per q-column = per lane, reduce over g groups)
    float mt = -1e30f;
#pragma unroll
    for (int kt = 0; kt < 4; ++kt)
#pragma unroll
      for (int r = 0; r < 4; ++r) mt = fmaxf(mt, sacc[kt][r]);
    mt = fmaxf(mt, __shfl_xor(mt, 16));
    mt = fmaxf(mt, __shfl_xor(mt, 32));
    const float mnew = fmaxf(mrun, mt);
    const float alpha = __expf(mrun - mnew);
    float psum = 0.f;
    u16* php = Ph[w] + lr * PSt;
    u16* plp = Pl[w] + lr * PSt;
#pragma unroll
    for (int kt = 0; kt < 4; ++kt) {
      u16 hh[4], ll[4];
#pragma unroll
      for (int r = 0; r < 4; ++r) {
        const float p = __expf(sacc[kt][r] - mnew);
        psum += p;
        hh[r] = f2bf(p);
        ll[r] = f2bf(p - bf2f(hh[r]));
      }
      uint2 wh, wl;
      wh.x = (unsigned)hh[0] | ((unsigned)hh[1] << 16);
      wh.y = (unsigned)hh[2] | ((unsigned)hh[3] << 16);
      wl.x = (unsigned)ll[0] | ((unsigned)ll[1] << 16);
      wl.y = (unsigned)ll[2] | ((unsigned)ll[3] << 16);
      *(uint2*)(php + kt * 16 + g * 4) = wh;      // P[q=lr][k=16kt+4g+r]
      *(uint2*)(plp + kt * 16 + g * 4) = wl;
    }
    psum += __shfl_xor(psum, 16);
    psum += __shfl_xor(psum, 32);
    mrun = mnew;
    lrun = lrun * alpha + psum;
#pragma unroll
    for (int dt = 0; dt < 4; ++dt) {
      oacc[dt][0] *= alpha; oacc[dt][1] *= alpha;
      oacc[dt][2] *= alpha; oacc[dt][3] *= alpha;
    }
    __syncthreads();                // P visible to all lanes (cross-lane LDS dep)

    // --- O^T += V^T·P^T, split-2 (Vh·Ph + Vl·Ph + Vh·Pl)
    const short8 pbh0 = *(const short8*)(php + g * 8);
    const short8 pbh1 = *(const short8*)(php + 32 + g * 8);
    const short8 pbl0 = *(const short8*)(plp + g * 8);
    const short8 pbl1 = *(const short8*)(plp + 32 + g * 8);
#pragma unroll
    for (int dt = 0; dt < 4; ++dt) {
      const u16* vap = Vh + (dt * 16 + lr) * KS + g * 8;
      const u16* vlp2 = Vlo + (dt * 16 + lr) * KS + g * 8;
      const short8 vh0 = *(const short8*)vap;
      const short8 vh1 = *(const short8*)(vap + 32);
      const short8 vl0 = *(const short8*)vlp2;
      const short8 vl1 = *(const short8*)(vlp2 + 32);
      oacc[dt] = __builtin_amdgcn_mfma_f32_16x16x32_bf16(vh0, pbh0, oacc[dt], 0, 0, 0);
      oacc[dt] = __builtin_amdgcn_mfma_f32_16x16x32_bf16(vl0, pbh0, oacc[dt], 0, 0, 0);
      oacc[dt] = __builtin_amdgcn_mfma_f32_16x16x32_bf16(vh0, pbl0, oacc[dt], 0, 0, 0);
      oacc[dt] = __builtin_amdgcn_mfma_f32_16x16x32_bf16(vh1, pbh1, oacc[dt], 0, 0, 0);
      oacc[dt] = __builtin_amdgcn_mfma_f32_16x16x32_bf16(vl1, pbh1, oacc[dt], 0, 0, 0);
      oacc[dt] = __builtin_amdgcn_mfma_f32_16x16x32_bf16(vh1, pbl1, oacc[dt], 0, 0, 0);
    }
  }

  // --- epilogue: o[q][d] = O^T[d][q] / l
  const float invl = 1.0f / lrun;
  float* ob = obuf + (size_t)(b * Tc + qrow) * 1024 + h * 64;
#pragma unroll
  for (int dt = 0; dt < 4; ++dt) {
    float4 o4;
    o4.x = oacc[dt][0] * invl; o4.y = oacc[dt][1] * invl;
    o4.z = oacc[dt][2] * invl; o4.w = oacc[dt][3] * invl;
    *(float4*)(ob + dt * 16 + g * 4) = o4;
  }
}

// ---------------------------------------------------------------- router (fp32) + top-2 append
__global__ __launch_bounds__(256) void router_kernel(const float* __restrict__ x2,
                                                     const float* __restrict__ rw,
                                                     int* __restrict__ cnt,
                                                     int* __restrict__ tok,
                                                     float* __restrict__ wt) {
  __shared__ float xr[1024];
  __shared__ float part[8][32];
  __shared__ float lg[8];
  const int row = blockIdx.x, tid = threadIdx.x;
  reinterpret_cast<float4*>(xr)[tid] = reinterpret_cast<const float4*>(x2 + (size_t)row * Dc)[tid];
  __syncthreads();
  const int e = tid >> 5, j = tid & 31;
  float p = 0.f;
  for (int d = j; d < Dc; d += 32) p += xr[d] * rw[e * Dc + d];
  part[e][j] = p;
  __syncthreads();
  if (tid < 8) {
    float s = 0.f;
    for (int q = 0; q < 32; ++q) s += part[tid][q];
    lg[tid] = s;
  }
  __syncthreads();
  if (tid == 0) {
    int i0 = 0;
    for (int q = 1; q < 8; ++q) if (lg[q] > lg[i0]) i0 = q;
    int i1 = (i0 == 0) ? 1 : 0;
    for (int q = 0; q < 8; ++q) if (q != i0 && lg[q] > lg[i1]) i1 = q;
    float mx = lg[0];
    for (int q = 1; q < 8; ++q) mx = fmaxf(mx, lg[q]);
    float ex[8], s = 0.f;
    for (int q = 0; q < 8; ++q) { ex[q] = expf(lg[q] - mx); s += ex[q]; }
    const float inv = 1.f / s;
    float p0v = fminf(fmaxf(ex[i0] * inv + 1e-9f, 1e-9f), 1.f - 1e-9f);
    float p1v = fminf(fmaxf(ex[i1] * inv + 1e-9f, 1e-9f), 1.f - 1e-9f);
    const float sw = 1.f / (p0v + p1v);
    int p0 = atomicAdd(&cnt[i0], 1);
    tok[i0 * Mtok + p0] = row; wt[i0 * Mtok + p0] = p0v * sw;
    int p1 = atomicAdd(&cnt[i1], 1);
    tok[i1 * Mtok + p1] = row; wt[i1 * Mtok + p1] = p1v * sw;
  }
}

// ---------------------------------------------------------------- expert GEMM1: gather -> gelu -> hid
__global__ __launch_bounds__(256) void gemm_e1_kernel(const u16* __restrict__ x2b,
                                                      const u16* __restrict__ w1,
                                                      const int* __restrict__ cnt,
                                                      const int* __restrict__ tok,
                                                      u16* __restrict__ hid) {
  const int bn = blockIdx.x;            // FF/128 = 32
  const int e = blockIdx.y >> 5, it = blockIdx.y & 31;
  const int n_e = cnt[e];
  if (it * 128 >= n_e) return;
  int offs = 0;
  for (int q = 0; q < 8; ++q) offs += (q < e) ? cnt[q] : 0;
  __shared__ u16 As[128 * 32], Bs[128 * 32];
  const int tid = threadIdx.x;
  const int r = tid >> 2, kk = (tid & 3) * 8;
  const int i0 = it * 128 + r, i1 = i0 + 64;
  const int t0 = tok[e * Mtok + ((i0 < n_e) ? i0 : (n_e - 1))];
  const int t1 = tok[e * Mtok + ((i1 < n_e) ? i1 : (n_e - 1))];
  const u16* a0 = x2b + (size_t)t0 * 1024 + kk;
  const u16* a1 = x2b + (size_t)t1 * 1024 + kk;
  const u16* b0 = w1 + (size_t)e * FFc * Dc + (size_t)(bn * 128 + r) * 1024 + kk;
  const u16* b1 = b0 + (size_t)64 * 1024;
  f32x4 acc[4][4] = {};
  gemm_mfma_core(a0, a1, b0, b1, 1024, As, Bs, acc);
  const int lane = tid & 63, wave = tid >> 6;
  const int wm = (wave & 1) * 64, wn = (wave >> 1) * 64;
  const int col = lane & 15, rb = (lane >> 4) * 4;
#pragma unroll
  for (int mt = 0; mt < 4; ++mt)
#pragma unroll
    for (int rr = 0; rr < 4; ++rr) {
      const int i = it * 128 + wm + mt * 16 + rb + rr;
      if (i < n_e) {
        const size_t hrow = (size_t)(offs + i) * FFc;
#pragma unroll
        for (int nt = 0; nt < 4; ++nt) {
          const int n = bn * 128 + wn + nt * 16 + col;
          hid[hrow + n] = f2bf(gelu_f(acc[mt][nt][rr]));
        }
      }
    }
}

// ---------------------------------------------------------------- expert GEMM2: hid x w2^T -> scatter-add
__global__ __launch_bounds__(256) void gemm_e2_kernel(const u16* __restrict__ hid,
                                                      const u16* __restrict__ w2,
                                                      const int* __restrict__ cnt,
                                                      const int* __restrict__ tok,
                                                      const float* __restrict__ wt,
                                                      float* __restrict__ out) {
  const int bn = blockIdx.x;            // D/128 = 8
  const int e = blockIdx.y >> 5, it = blockIdx.y & 31;
  const int n_e = cnt[e];
  if (it * 128 >= n_e) return;
  int offs = 0;
  for (int q = 0; q < 8; ++q) offs += (q < e) ? cnt[q] : 0;
  __shared__ u16 As[128 * 32], Bs[128 * 32];
  const int tid = threadIdx.x;
  const int r = tid >> 2, kk = (tid & 3) * 8;
  const int i0 = it * 128 + r, i1 = i0 + 64;
  const int ri0 = offs + ((i0 < n_e) ? i0 : (n_e - 1));
  const int ri1 = offs + ((i1 < n_e) ? i1 : (n_e - 1));
  const u16* a0 = hid + (size_t)ri0 * FFc + kk;
  const u16* a1 = hid + (size_t)ri1 * FFc + kk;
  const u16* b0 = w2 + (size_t)e * Dc * FFc + (size_t)(bn * 128 + r) * FFc + kk;
  const u16* b1 = b0 + (size_t)64 * FFc;
  f32x4 acc[4][4] = {};
  gemm_mfma_core(a0, a1, b0, b1, FFc, As, Bs, acc);
  const int lane = tid & 63, wave = tid >> 6;
  const int wm = (wave & 1) * 64, wn = (wave >> 1) * 64;
  const int col = lane & 15, rb = (lane >> 4) * 4;
#pragma unroll
  for (int mt = 0; mt < 4; ++mt)
#pragma unroll
    for (int rr = 0; rr < 4; ++rr) {
      const int i = it * 128 + wm + mt * 16 + rb + rr;
      if (i < n_e) {
        const int tk = tok[e * Mtok + i];
        const float wgt = wt[e * Mtok + i];
#pragma unroll
        for (int nt = 0; nt < 4; ++nt) {
          const int n = bn * 128 + wn + nt * 16 + col;
          atomicAdd(&out[(size_t)tk * 1024 + n], wgt * acc[mt][nt][rr]);
        }
      }
    }
}

// ---------------------------------------------------------------- workspace layout (bytes)
constexpr size_t OFF_WQKV3 = 0;                                       // 18,874,368
constexpr size_t OFF_WPROJ3 = 18874368;                               //  6,291,456
constexpr size_t OFF_W1 = 25165824;                                   // 67,108,864
constexpr size_t OFF_W2 = 92274688;                                   // 67,108,864
constexpr size_t OFF_HPL = 159383552;                                 // 25,165,824
constexpr size_t OFF_QKV = 184549376;                                 // 50,331,648 (later hid overlay)
constexpr size_t OFF_OF = 234881024;                                  // 16,777,216
constexpr size_t OFF_X2 = 251658240;                                  //  8,388,608
constexpr size_t OFF_CNT = 260046848;
constexpr size_t OFF_TOK = OFF_CNT + 256;
constexpr size_t OFF_WTL = OFF_TOK + (size_t)Ec * Mtok * 4;

extern "C" void kernel_launch(void* const* d_in, const int* in_sizes, int n_in,
                              void* d_out, int out_size, void* d_ws, size_t ws_size,
                              hipStream_t stream) {
  const float* x = (const float*)d_in[0];
  const float* c = (const float*)d_in[1];
  const float* ln1_w = (const float*)d_in[2];
  const float* w_qkv = (const float*)d_in[3];
  const float* w_proj = (const float*)d_in[4];
  const float* ln2_w = (const float*)d_in[5];
  const float* router_w = (const float*)d_in[6];
  const float* ew1 = (const float*)d_in[7];
  const float* ew2 = (const float*)d_in[8];
  float* out = (float*)d_out;
  char* ws = (char*)d_ws;

  u16* wqkv3 = (u16*)(ws + OFF_WQKV3);
  u16* wproj3 = (u16*)(ws + OFF_WPROJ3);
  u16* w1_bf = (u16*)(ws + OFF_W1);
  u16* w2_bf = (u16*)(ws + OFF_W2);
  u16* hpl = (u16*)(ws + OFF_HPL);       // h planes, later o planes
  float* qkvf = (float*)(ws + OFF_QKV);
  float* of = (float*)(ws + OFF_OF);     // o fp32, later xmid fp32
  u16* x2_bf = (u16*)(ws + OFF_X2);
  u16* hid_bf = (u16*)(ws + OFF_QKV);    // overlay (qkv+of dead by expert phase)
  int* cnt = (int*)(ws + OFF_CNT);
  int* tok = (int*)(ws + OFF_TOK);
  float* wtl = (float*)(ws + OFF_WTL);

  // 1) weight conversions (inputs restored every call)
  split3_kernel<<<(3 * Dc * Dc / 4 + 255) / 256, 256, 0, stream>>>(w_qkv, wqkv3, PS_WQKV, 3 * Dc * Dc / 4);
  split3_kernel<<<(Dc * Dc / 4 + 255) / 256, 256, 0, stream>>>(w_proj, wproj3, PS_WPROJ, Dc * Dc / 4);
  {
    int n4 = Ec * FFc * Dc / 4;
    cvt_bf16_kernel<<<(n4 + 255) / 256, 256, 0, stream>>>(ew1, w1_bf, n4);
    cvt_bf16_kernel<<<(n4 + 255) / 256, 256, 0, stream>>>(ew2, w2_bf, n4);
  }
  // 2) h = LN1(x)*w + c -> 3 bf16 planes
  ln1_kernel<<<Mtok, 256, 0, stream>>>(x, ln1_w, c, hpl);
  // 3) qkv = h @ w_qkv^T  (split-3, fp32 out)
  gemm_qkv_kernel<<<dim3(24, 32), 256, 0, stream>>>(hpl, wqkv3, qkvf);
  // 4) causal attention, bf16 split-2 MFMA flash (64 q rows per block)
  attn_mfma_kernel<<<dim3(Tc / 64, Bc * Hc), 256, 0, stream>>>(qkvf, of);
  // 5) split o -> planes (h planes dead)
  split3_kernel<<<(Mtok * Dc / 4 + 255) / 256, 256, 0, stream>>>(of, hpl, PS_H, Mtok * Dc / 4);
  // 6) xmid = x + o @ w_proj^T  (split-3, fp32 out; overwrites o fp32)
  gemm_proj_kernel<<<dim3(8, 32), 256, 0, stream>>>(hpl, wproj3, x, of);
  // 7) x2 = LN2(xmid): fp32 -> d_out, bf16 -> x2_bf
  ln2_kernel<<<Mtok, 256, 0, stream>>>(of, ln2_w, out, x2_bf);
  // 8) router -> per-expert token lists
  (void)hipMemsetAsync(cnt, 0, Ec * sizeof(int), stream);
  router_kernel<<<Mtok, 256, 0, stream>>>(out, router_w, cnt, tok, wtl);
  // 9) experts (sparse top-2, bf16 MFMA)
  gemm_e1_kernel<<<dim3(32, 256), 256, 0, stream>>>(x2_bf, w1_bf, cnt, tok, hid_bf);
  gemm_e2_kernel<<<dim3(8, 256), 256, 0, stream>>>(hid_bf, w2_bf, cnt, tok, wtl, out);
}

// Round 2
// 1031.922 us; speedup vs baseline: 1.4281x; 1.1173x over previous
//
#include <hip/hip_runtime.h>
#include <cstdint>
#include <cstddef>

// ---------------------------------------------------------------------------
// NoiseBlockMoE (B=4,T=1024,D=1024,H=16,E=8,top2,FF=4096)
// Round 5: dense GEMMs (qkv/proj) moved from split-3 bf16 (6 sweeps) to
// split-2 fp16 (hi + lo*2^12, dual accumulator, 3 products) with SHARED
// staging: all 4 planes staged once per k-step, 48 MFMAs per 16 ds_reads.
// XOR bank swizzle (source-permuted, per rule both-sides) on all GEMM cores.
// Experts moved bf16 -> fp16 (same rate, 8x less quantization error).
// Attention kernel unchanged from round 4.
// ---------------------------------------------------------------------------

#define AS1 __attribute__((address_space(1)))
#define AS3 __attribute__((address_space(3)))

typedef unsigned short u16;
typedef __attribute__((ext_vector_type(8))) short short8;     // 8 bf16 = 4 VGPR
typedef __attribute__((ext_vector_type(8))) _Float16 half8;   // 8 fp16 = 4 VGPR
typedef __attribute__((ext_vector_type(4))) float f32x4;

constexpr int Bc = 4, Tc = 1024, Dc = 1024, Hc = 16, Ec = 8, FFc = 4096;
constexpr int Mtok = Bc * Tc;   // 4096 tokens

// plane strides (elements)
constexpr size_t PS_WQKV = (size_t)3 * Dc * Dc;   // 3145728
constexpr size_t PS_WPROJ = (size_t)Dc * Dc;      // 1048576
constexpr size_t PS_H = (size_t)Mtok * Dc;        // 4194304

constexpr float LO_SCALE = 4096.0f;               // 2^12
constexpr float LO_INV = 1.0f / 4096.0f;

__device__ __forceinline__ u16 f2bf(float f) {              // RNE f32->bf16
  unsigned u = __float_as_uint(f);
  u += 0x7fffu + ((u >> 16) & 1u);
  return (u16)(u >> 16);
}
__device__ __forceinline__ float bf2f(u16 v) { return __uint_as_float(((unsigned)v) << 16); }
__device__ __forceinline__ u16 f2h(float f) {               // RNE f32->fp16
  _Float16 h = (_Float16)f;
  return *(u16*)&h;
}
__device__ __forceinline__ float h2f(u16 v) {
  _Float16 h = *(_Float16*)&v;
  return (float)h;
}
__device__ __forceinline__ float gelu_f(float v) {          // exact GELU (erf)
  return 0.5f * v * (1.0f + erff(v * 0.70710678118654752440f));
}

// ---------------------------------------------------------------- cvt f32->fp16 (plain)
__global__ __launch_bounds__(256) void cvt_fp16_kernel(const float* __restrict__ in,
                                                       u16* __restrict__ out, int n4) {
  int i = blockIdx.x * 256 + threadIdx.x;
  if (i >= n4) return;
  float4 v = reinterpret_cast<const float4*>(in)[i];
  uint2 o;
  o.x = (unsigned)f2h(v.x) | ((unsigned)f2h(v.y) << 16);
  o.y = (unsigned)f2h(v.z) | ((unsigned)f2h(v.w) << 16);
  reinterpret_cast<uint2*>(out)[i] = o;
}

// ---------------------------------------------------------------- fp32 -> 2 fp16 planes (lo*2^12)
__global__ __launch_bounds__(256) void split2h_kernel(const float* __restrict__ in,
                                                      u16* __restrict__ out,
                                                      size_t ps, int n4) {
  int i = blockIdx.x * 256 + threadIdx.x;
  if (i >= n4) return;
  float4 v = reinterpret_cast<const float4*>(in)[i];
  float a[4] = {v.x, v.y, v.z, v.w};
  unsigned h[4], lo[4];
#pragma unroll
  for (int j = 0; j < 4; ++j) {
    u16 hh = f2h(a[j]);
    float r = (a[j] - h2f(hh)) * LO_SCALE;
    h[j] = hh; lo[j] = f2h(r);
  }
  uint2 o0, o1;
  o0.x = h[0] | (h[1] << 16);   o0.y = h[2] | (h[3] << 16);
  o1.x = lo[0] | (lo[1] << 16); o1.y = lo[2] | (lo[3] << 16);
  const size_t base = (size_t)i * 4;
  *(uint2*)&out[base] = o0;
  *(uint2*)&out[ps + base] = o1;
}

// ---------------------------------------------------------------- LN1 (+c) -> 2 fp16 planes
__global__ __launch_bounds__(256) void ln1_kernel(const float* __restrict__ x,
                                                  const float* __restrict__ w,
                                                  const float* __restrict__ c,
                                                  u16* __restrict__ hp) {
  const int row = blockIdx.x, tid = threadIdx.x;
  const int b = row >> 10;   // T=1024
  const float4 v = reinterpret_cast<const float4*>(x + (size_t)row * Dc)[tid];
  __shared__ float red[256];
  red[tid] = v.x + v.y + v.z + v.w;
  __syncthreads();
  for (int s = 128; s > 0; s >>= 1) { if (tid < s) red[tid] += red[tid + s]; __syncthreads(); }
  const float mu = red[0] * (1.0f / Dc);
  __syncthreads();
  const float dx = v.x - mu, dy = v.y - mu, dz = v.z - mu, dw = v.w - mu;
  red[tid] = dx * dx + dy * dy + dz * dz + dw * dw;
  __syncthreads();
  for (int s = 128; s > 0; s >>= 1) { if (tid < s) red[tid] += red[tid + s]; __syncthreads(); }
  const float rs = rsqrtf(red[0] * (1.0f / Dc) + 1e-5f);
  const float4 wv = reinterpret_cast<const float4*>(w)[tid];
  const float4 cv = reinterpret_cast<const float4*>(c + (size_t)b * Dc)[tid];
  float a[4];
  a[0] = dx * rs * wv.x + cv.x; a[1] = dy * rs * wv.y + cv.y;
  a[2] = dz * rs * wv.z + cv.z; a[3] = dw * rs * wv.w + cv.w;
  unsigned h[4], lo[4];
#pragma unroll
  for (int j = 0; j < 4; ++j) {
    u16 hh = f2h(a[j]);
    float r = (a[j] - h2f(hh)) * LO_SCALE;
    h[j] = hh; lo[j] = f2h(r);
  }
  uint2 o0, o1;
  o0.x = h[0] | (h[1] << 16);   o0.y = h[2] | (h[3] << 16);
  o1.x = lo[0] | (lo[1] << 16); o1.y = lo[2] | (lo[3] << 16);
  const size_t base = (size_t)row * Dc + tid * 4;
  *(uint2*)&hp[base] = o0;
  *(uint2*)&hp[PS_H + base] = o1;
}

// ---------------------------------------------------------------- LN2 -> f32 (d_out) + fp16
__global__ __launch_bounds__(256) void ln2_kernel(const float* __restrict__ xin,
                                                  const float* __restrict__ w,
                                                  float* __restrict__ xf,
                                                  u16* __restrict__ xb) {
  const int row = blockIdx.x, tid = threadIdx.x;
  const float4 v = reinterpret_cast<const float4*>(xin + (size_t)row * Dc)[tid];
  __shared__ float red[256];
  red[tid] = v.x + v.y + v.z + v.w;
  __syncthreads();
  for (int s = 128; s > 0; s >>= 1) { if (tid < s) red[tid] += red[tid + s]; __syncthreads(); }
  const float mu = red[0] * (1.0f / Dc);
  __syncthreads();
  const float dx = v.x - mu, dy = v.y - mu, dz = v.z - mu, dw = v.w - mu;
  red[tid] = dx * dx + dy * dy + dz * dz + dw * dw;
  __syncthreads();
  for (int s = 128; s > 0; s >>= 1) { if (tid < s) red[tid] += red[tid + s]; __syncthreads(); }
  const float rs = rsqrtf(red[0] * (1.0f / Dc) + 1e-5f);
  const float4 wv = reinterpret_cast<const float4*>(w)[tid];
  float4 ov;
  ov.x = dx * rs * wv.x; ov.y = dy * rs * wv.y; ov.z = dz * rs * wv.z; ov.w = dw * rs * wv.w;
  reinterpret_cast<float4*>(xf + (size_t)row * Dc)[tid] = ov;
  uint2 o;
  o.x = (unsigned)f2h(ov.x) | ((unsigned)f2h(ov.y) << 16);
  o.y = (unsigned)f2h(ov.z) | ((unsigned)f2h(ov.w) << 16);
  reinterpret_cast<uint2*>(xb + (size_t)row * Dc)[tid] = o;
}

// ---------------------------------------------------------------- fp16 GEMM core (single plane, swizzled)
// LDS layout: [128][32] u16, with the 16B slot index XOR-swizzled by (row&3).
// Source permutation at staging (caller passes kk = ((tid&3)^(r&3))*8) keeps
// global_load_lds destinations linear while the logical layout is swizzled.
__device__ __forceinline__ void gemm_f16_core(const u16* a0, const u16* a1,
                                              const u16* b0, const u16* b1,
                                              int K, u16* As, u16* Bs, f32x4 acc[4][4]) {
  const int tid = threadIdx.x;
  const int lane = tid & 63;
  const int wave = tid >> 6;
  const int wm = (wave & 1) * 64;
  const int wn = (wave >> 1) * 64;
  const int frow = lane & 15;
  const int gs = (((lane >> 4) ^ (frow & 3))) * 8;     // swizzled 16B slot
  int aoff[4], boff[4];
#pragma unroll
  for (int t = 0; t < 4; ++t) {
    aoff[t] = (wm + t * 16 + frow) * 32 + gs;
    boff[t] = (wn + t * 16 + frow) * 32 + gs;
  }
  const int lds0 = tid * 8;
  for (int k0 = 0; k0 < K; k0 += 32) {
    __builtin_amdgcn_global_load_lds((AS1 void*)a0, (AS3 void*)(As + lds0), 16, 0, 0);
    __builtin_amdgcn_global_load_lds((AS1 void*)a1, (AS3 void*)(As + 2048 + lds0), 16, 0, 0);
    __builtin_amdgcn_global_load_lds((AS1 void*)b0, (AS3 void*)(Bs + lds0), 16, 0, 0);
    __builtin_amdgcn_global_load_lds((AS1 void*)b1, (AS3 void*)(Bs + 2048 + lds0), 16, 0, 0);
    a0 += 32; a1 += 32; b0 += 32; b1 += 32;
    __syncthreads();
    half8 af[4], bfr[4];
#pragma unroll
    for (int t = 0; t < 4; ++t) af[t] = *(const half8*)(As + aoff[t]);
#pragma unroll
    for (int t = 0; t < 4; ++t) bfr[t] = *(const half8*)(Bs + boff[t]);
#pragma unroll
    for (int mt = 0; mt < 4; ++mt)
#pragma unroll
      for (int nt = 0; nt < 4; ++nt)
        acc[mt][nt] = __builtin_amdgcn_mfma_f32_16x16x32_f16(af[mt], bfr[nt], acc[mt][nt], 0, 0, 0);
    __syncthreads();
  }
}

// ---------------------------------------------------------------- fp16 split-2 core, SHARED staging
// Stages Ah,Al,Bh,Bl (4 x 8KB) once per k-step; 48 MFMAs per 16 ds_reads.
// acc0 accumulates Ah*Bh; acc1 accumulates Al*Bh + Ah*Bl (value scale 2^12).
__device__ __forceinline__ void gemm_f16s2_core(const u16* ah0, const u16* ah1,
                                                const u16* al0, const u16* al1,
                                                const u16* bh0, const u16* bh1,
                                                const u16* bl0, const u16* bl1,
                                                int K, u16* S,
                                                f32x4 acc0[4][4], f32x4 acc1[4][4]) {
  const int tid = threadIdx.x;
  const int lane = tid & 63;
  const int wave = tid >> 6;
  const int wm = (wave & 1) * 64;
  const int wn = (wave >> 1) * 64;
  const int frow = lane & 15;
  const int gs = (((lane >> 4) ^ (frow & 3))) * 8;
  int aoff[4], boff[4];
#pragma unroll
  for (int t = 0; t < 4; ++t) {
    aoff[t] = (wm + t * 16 + frow) * 32 + gs;
    boff[t] = (wn + t * 16 + frow) * 32 + gs;
  }
  const int lds0 = tid * 8;
  for (int k0 = 0; k0 < K; k0 += 32) {
    __builtin_amdgcn_global_load_lds((AS1 void*)ah0, (AS3 void*)(S + lds0), 16, 0, 0);
    __builtin_amdgcn_global_load_lds((AS1 void*)ah1, (AS3 void*)(S + 2048 + lds0), 16, 0, 0);
    __builtin_amdgcn_global_load_lds((AS1 void*)al0, (AS3 void*)(S + 4096 + lds0), 16, 0, 0);
    __builtin_amdgcn_global_load_lds((AS1 void*)al1, (AS3 void*)(S + 6144 + lds0), 16, 0, 0);
    __builtin_amdgcn_global_load_lds((AS1 void*)bh0, (AS3 void*)(S + 8192 + lds0), 16, 0, 0);
    __builtin_amdgcn_global_load_lds((AS1 void*)bh1, (AS3 void*)(S + 10240 + lds0), 16, 0, 0);
    __builtin_amdgcn_global_load_lds((AS1 void*)bl0, (AS3 void*)(S + 12288 + lds0), 16, 0, 0);
    __builtin_amdgcn_global_load_lds((AS1 void*)bl1, (AS3 void*)(S + 14336 + lds0), 16, 0, 0);
    ah0 += 32; ah1 += 32; al0 += 32; al1 += 32;
    bh0 += 32; bh1 += 32; bl0 += 32; bl1 += 32;
    __syncthreads();
    half8 ahf[4], bhf[4];
#pragma unroll
    for (int t = 0; t < 4; ++t) {
      ahf[t] = *(const half8*)(S + aoff[t]);
      bhf[t] = *(const half8*)(S + 8192 + boff[t]);
    }
#pragma unroll
    for (int mt = 0; mt < 4; ++mt)
#pragma unroll
      for (int nt = 0; nt < 4; ++nt)
        acc0[mt][nt] = __builtin_amdgcn_mfma_f32_16x16x32_f16(ahf[mt], bhf[nt], acc0[mt][nt], 0, 0, 0);
    {
      half8 alf[4];
#pragma unroll
      for (int t = 0; t < 4; ++t) alf[t] = *(const half8*)(S + 4096 + aoff[t]);
#pragma unroll
      for (int mt = 0; mt < 4; ++mt)
#pragma unroll
        for (int nt = 0; nt < 4; ++nt)
          acc1[mt][nt] = __builtin_amdgcn_mfma_f32_16x16x32_f16(alf[mt], bhf[nt], acc1[mt][nt], 0, 0, 0);
    }
    {
      half8 blf[4];
#pragma unroll
      for (int t = 0; t < 4; ++t) blf[t] = *(const half8*)(S + 12288 + boff[t]);
#pragma unroll
      for (int mt = 0; mt < 4; ++mt)
#pragma unroll
        for (int nt = 0; nt < 4; ++nt)
          acc1[mt][nt] = __builtin_amdgcn_mfma_f32_16x16x32_f16(ahf[mt], blf[nt], acc1[mt][nt], 0, 0, 0);
    }
    __syncthreads();
  }
}

// ---------------------------------------------------------------- qkv split-2 GEMM -> fp32
__global__ __launch_bounds__(256) void gemm_qkv_kernel(const u16* __restrict__ A,
                                                       const u16* __restrict__ Bw,
                                                       float* __restrict__ Cout) {
  __shared__ u16 S[4 * 4096];   // 32KB: Ah, Al, Bh, Bl
  const int bn = blockIdx.x, bm = blockIdx.y, tid = threadIdx.x;
  const int r = tid >> 2, kk = ((tid & 3) ^ (r & 3)) * 8;
  const u16* ah0 = A + (size_t)(bm * 128 + r) * 1024 + kk;
  const u16* ah1 = ah0 + (size_t)64 * 1024;
  const u16* bh0 = Bw + (size_t)(bn * 128 + r) * 1024 + kk;
  const u16* bh1 = bh0 + (size_t)64 * 1024;
  f32x4 acc0[4][4] = {}, acc1[4][4] = {};
  gemm_f16s2_core(ah0, ah1, ah0 + PS_H, ah1 + PS_H,
                  bh0, bh1, bh0 + PS_WQKV, bh1 + PS_WQKV,
                  1024, S, acc0, acc1);
  const int lane = tid & 63, wave = tid >> 6;
  const int wm = (wave & 1) * 64, wn = (wave >> 1) * 64;
  const int col = lane & 15, rb = (lane >> 4) * 4;
#pragma unroll
  for (int mt = 0; mt < 4; ++mt)
#pragma unroll
    for (int rr = 0; rr < 4; ++rr) {
      const int m = bm * 128 + wm + mt * 16 + rb + rr;
#pragma unroll
      for (int nt = 0; nt < 4; ++nt) {
        const int n = bn * 128 + wn + nt * 16 + col;
        Cout[(size_t)m * 3072 + n] = acc0[mt][nt][rr] + acc1[mt][nt][rr] * LO_INV;
      }
    }
}

// ---------------------------------------------------------------- proj split-2 GEMM + residual -> fp32
__global__ __launch_bounds__(256) void gemm_proj_kernel(const u16* __restrict__ A,
                                                        const u16* __restrict__ Bw,
                                                        const float* __restrict__ xres,
                                                        float* __restrict__ xmid) {
  __shared__ u16 S[4 * 4096];
  const int bn = blockIdx.x, bm = blockIdx.y, tid = threadIdx.x;
  const int r = tid >> 2, kk = ((tid & 3) ^ (r & 3)) * 8;
  const u16* ah0 = A + (size_t)(bm * 128 + r) * 1024 + kk;
  const u16* ah1 = ah0 + (size_t)64 * 1024;
  const u16* bh0 = Bw + (size_t)(bn * 128 + r) * 1024 + kk;
  const u16* bh1 = bh0 + (size_t)64 * 1024;
  f32x4 acc0[4][4] = {}, acc1[4][4] = {};
  gemm_f16s2_core(ah0, ah1, ah0 + PS_H, ah1 + PS_H,
                  bh0, bh1, bh0 + PS_WPROJ, bh1 + PS_WPROJ,
                  1024, S, acc0, acc1);
  const int lane = tid & 63, wave = tid >> 6;
  const int wm = (wave & 1) * 64, wn = (wave >> 1) * 64;
  const int col = lane & 15, rb = (lane >> 4) * 4;
#pragma unroll
  for (int mt = 0; mt < 4; ++mt)
#pragma unroll
    for (int rr = 0; rr < 4; ++rr) {
      const int m = bm * 128 + wm + mt * 16 + rb + rr;
#pragma unroll
      for (int nt = 0; nt < 4; ++nt) {
        const int n = bn * 128 + wn + nt * 16 + col;
        xmid[(size_t)m * 1024 + n] =
            xres[(size_t)m * 1024 + n] + acc0[mt][nt][rr] + acc1[mt][nt][rr] * LO_INV;
      }
    }
}

// ---------------------------------------------------------------- attention, bf16 split-2 MFMA flash
// (unchanged from round 4)
__global__ __launch_bounds__(256, 3) void attn_mfma_kernel(const float* __restrict__ qkv,
                                                           float* __restrict__ obuf) {
  constexpr int KS = 72;    // K/V row stride (u16)
  constexpr int PSt = 68;   // P row stride (u16)
  __shared__ u16 Kh[64 * KS], Klo[64 * KS];
  __shared__ u16 Vh[64 * KS], Vlo[64 * KS];
  __shared__ u16 Ph[4][16 * PSt], Pl[4][16 * PSt];

  const int tid = threadIdx.x, lane = tid & 63, w = tid >> 6;
  const int lr = lane & 15, g = lane >> 4;
  const int bh = blockIdx.y, b = bh >> 4, h = bh & 15;
  const int blk = blockIdx.x;
  const int qrow = blk * 64 + w * 16 + lr;

  short8 qh[2], ql[2];
  {
    const float* qp = qkv + (size_t)(b * Tc + qrow) * 3072 + h * 64 + g * 8;
    const float4 f0 = *(const float4*)(qp);
    const float4 f1 = *(const float4*)(qp + 4);
    const float4 f2 = *(const float4*)(qp + 32);
    const float4 f3 = *(const float4*)(qp + 36);
    const float qq[16] = {f0.x, f0.y, f0.z, f0.w, f1.x, f1.y, f1.z, f1.w,
                          f2.x, f2.y, f2.z, f2.w, f3.x, f3.y, f3.z, f3.w};
#pragma unroll
    for (int s = 0; s < 2; ++s)
#pragma unroll
      for (int j = 0; j < 8; ++j) {
        const float v = qq[s * 8 + j] * 0.125f;
        const u16 hi = f2bf(v);
        qh[s][j] = (short)hi;
        ql[s][j] = (short)f2bf(v - bf2f(hi));
      }
  }

  const int tkl = (tid & 31) * 2;
  const int td0 = (tid >> 5) * 8;
  const float* kgb = qkv + (size_t)b * Tc * 3072 + 1024 + h * 64;
  const float* vgb = kgb + 1024;

  f32x4 oacc[4] = {};
  float mrun = -1e30f, lrun = 0.f;

  for (int c = 0; c <= blk; ++c) {
    const int k0 = c * 64;
    __syncthreads();
    {
      const float* kr0 = kgb + (size_t)(k0 + tkl) * 3072 + td0;
      const float* kr1 = kr0 + 3072;
      const float* vr0 = vgb + (size_t)(k0 + tkl) * 3072 + td0;
      const float* vr1 = vr0 + 3072;
      const float4 ka0 = *(const float4*)kr0, ka1 = *(const float4*)(kr0 + 4);
      const float4 kb0 = *(const float4*)kr1, kb1 = *(const float4*)(kr1 + 4);
      const float4 va0 = *(const float4*)vr0, va1 = *(const float4*)(vr0 + 4);
      const float4 vb0 = *(const float4*)vr1, vb1 = *(const float4*)(vr1 + 4);
      const float ka[8] = {ka0.x, ka0.y, ka0.z, ka0.w, ka1.x, ka1.y, ka1.z, ka1.w};
      const float kb[8] = {kb0.x, kb0.y, kb0.z, kb0.w, kb1.x, kb1.y, kb1.z, kb1.w};
      const float va[8] = {va0.x, va0.y, va0.z, va0.w, va1.x, va1.y, va1.z, va1.w};
      const float vb[8] = {vb0.x, vb0.y, vb0.z, vb0.w, vb1.x, vb1.y, vb1.z, vb1.w};
      short8 kh0, kl0, kh1, kl1;
#pragma unroll
      for (int j = 0; j < 8; ++j) {
        const u16 h0 = f2bf(ka[j]); kh0[j] = (short)h0; kl0[j] = (short)f2bf(ka[j] - bf2f(h0));
        const u16 h1 = f2bf(kb[j]); kh1[j] = (short)h1; kl1[j] = (short)f2bf(kb[j] - bf2f(h1));
      }
      *(short8*)(Kh + tkl * KS + td0) = kh0;
      *(short8*)(Kh + (tkl + 1) * KS + td0) = kh1;
      *(short8*)(Klo + tkl * KS + td0) = kl0;
      *(short8*)(Klo + (tkl + 1) * KS + td0) = kl1;
#pragma unroll
      for (int i = 0; i < 8; ++i) {
        const u16 h0 = f2bf(va[i]); const u16 l0 = f2bf(va[i] - bf2f(h0));
        const u16 h1 = f2bf(vb[i]); const u16 l1 = f2bf(vb[i] - bf2f(h1));
        *(unsigned*)(Vh + (td0 + i) * KS + tkl) = (unsigned)h0 | ((unsigned)h1 << 16);
        *(unsigned*)(Vlo + (td0 + i) * KS + tkl) = (unsigned)l0 | ((unsigned)l1 << 16);
      }
    }
    __syncthreads();

    f32x4 sacc[4] = {};
#pragma unroll
    for (int kt = 0; kt < 4; ++kt) {
      const u16* kap = Kh + (kt * 16 + lr) * KS + g * 8;
      const u16* klp = Klo + (kt * 16 + lr) * KS + g * 8;
      const short8 ah0 = *(const short8*)kap;
      const short8 ah1 = *(const short8*)(kap + 32);
      const short8 al0 = *(const short8*)klp;
      const short8 al1 = *(const short8*)(klp + 32);
      sacc[kt] = __builtin_amdgcn_mfma_f32_16x16x32_bf16(ah0, qh[0], sacc[kt], 0, 0, 0);
      sacc[kt] = __builtin_amdgcn_mfma_f32_16x16x32_bf16(al0, qh[0], sacc[kt], 0, 0, 0);
      sacc[kt] = __builtin_amdgcn_mfma_f32_16x16x32_bf16(ah0, ql[0], sacc[kt], 0, 0, 0);
      sacc[kt] = __builtin_amdgcn_mfma_f32_16x16x32_bf16(ah1, qh[1], sacc[kt], 0, 0, 0);
      sacc[kt] = __builtin_amdgcn_mfma_f32_16x16x32_bf16(al1, qh[1], sacc[kt], 0, 0, 0);
      sacc[kt] = __builtin_amdgcn_mfma_f32_16x16x32_bf16(ah1, ql[1], sacc[kt], 0, 0, 0);
    }

    if (c == blk) {
#pragma unroll
      for (int kt = 0; kt < 4; ++kt)
#pragma unroll
        for (int r = 0; r < 4; ++r)
          if (k0 + kt * 16 + g * 4 + r > qrow) sacc[kt][r] = -1e30f;
    }

    float mt = -1e30f;
#pragma unroll
    for (int kt = 0; kt < 4; ++kt)
#pragma unroll
      for (int r = 0; r < 4; ++r) mt = fmaxf(mt, sacc[kt][r]);
    mt = fmaxf(mt, __shfl_xor(mt, 16));
    mt = fmaxf(mt, __shfl_xor(mt, 32));
    const float mnew = fmaxf(mrun, mt);
    const float alpha = __expf(mrun - mnew);
    float psum = 0.f;
    u16* php = Ph[w] + lr * PSt;
    u16* plp = Pl[w] + lr * PSt;
#pragma unroll
    for (int kt = 0; kt < 4; ++kt) {
      u16 hh[4], ll[4];
#pragma unroll
      for (int r = 0; r < 4; ++r) {
        const float p = __expf(sacc[kt][r] - mnew);
        psum += p;
        hh[r] = f2bf(p);
        ll[r] = f2bf(p - bf2f(hh[r]));
      }
      uint2 wh, wl;
      wh.x = (unsigned)hh[0] | ((unsigned)hh[1] << 16);
      wh.y = (unsigned)hh[2] | ((unsigned)hh[3] << 16);
      wl.x = (unsigned)ll[0] | ((unsigned)ll[1] << 16);
      wl.y = (unsigned)ll[2] | ((unsigned)ll[3] << 16);
      *(uint2*)(php + kt * 16 + g * 4) = wh;
      *(uint2*)(plp + kt * 16 + g * 4) = wl;
    }
    psum += __shfl_xor(psum, 16);
    psum += __shfl_xor(psum, 32);
    mrun = mnew;
    lrun = lrun * alpha + psum;
#pragma unroll
    for (int dt = 0; dt < 4; ++dt) {
      oacc[dt][0] *= alpha; oacc[dt][1] *= alpha;
      oacc[dt][2] *= alpha; oacc[dt][3] *= alpha;
    }
    __syncthreads();

    const short8 pbh0 = *(const short8*)(php + g * 8);
    const short8 pbh1 = *(const short8*)(php + 32 + g * 8);
    const short8 pbl0 = *(const short8*)(plp + g * 8);
    const short8 pbl1 = *(const short8*)(plp + 32 + g * 8);
#pragma unroll
    for (int dt = 0; dt < 4; ++dt) {
      const u16* vap = Vh + (dt * 16 + lr) * KS + g * 8;
      const u16* vlp2 = Vlo + (dt * 16 + lr) * KS + g * 8;
      const short8 vh0 = *(const short8*)vap;
      const short8 vh1 = *(const short8*)(vap + 32);
      const short8 vl0 = *(const short8*)vlp2;
      const short8 vl1 = *(const short8*)(vlp2 + 32);
      oacc[dt] = __builtin_amdgcn_mfma_f32_16x16x32_bf16(vh0, pbh0, oacc[dt], 0, 0, 0);
      oacc[dt] = __builtin_amdgcn_mfma_f32_16x16x32_bf16(vl0, pbh0, oacc[dt], 0, 0, 0);
      oacc[dt] = __builtin_amdgcn_mfma_f32_16x16x32_bf16(vh0, pbl0, oacc[dt], 0, 0, 0);
      oacc[dt] = __builtin_amdgcn_mfma_f32_16x16x32_bf16(vh1, pbh1, oacc[dt], 0, 0, 0);
      oacc[dt] = __builtin_amdgcn_mfma_f32_16x16x32_bf16(vl1, pbh1, oacc[dt], 0, 0, 0);
      oacc[dt] = __builtin_amdgcn_mfma_f32_16x16x32_bf16(vh1, pbl1, oacc[dt], 0, 0, 0);
    }
  }

  const float invl = 1.0f / lrun;
  float* ob = obuf + (size_t)(b * Tc + qrow) * 1024 + h * 64;
#pragma unroll
  for (int dt = 0; dt < 4; ++dt) {
    float4 o4;
    o4.x = oacc[dt][0] * invl; o4.y = oacc[dt][1] * invl;
    o4.z = oacc[dt][2] * invl; o4.w = oacc[dt][3] * invl;
    *(float4*)(ob + dt * 16 + g * 4) = o4;
  }
}

// ---------------------------------------------------------------- router (fp32) + top-2 append
__global__ __launch_bounds__(256) void router_kernel(const float* __restrict__ x2,
                                                     const float* __restrict__ rw,
                                                     int* __restrict__ cnt,
                                                     int* __restrict__ tok,
                                                     float* __restrict__ wt) {
  __shared__ float xr[1024];
  __shared__ float part[8][32];
  __shared__ float lg[8];
  const int row = blockIdx.x, tid = threadIdx.x;
  reinterpret_cast<float4*>(xr)[tid] = reinterpret_cast<const float4*>(x2 + (size_t)row * Dc)[tid];
  __syncthreads();
  const int e = tid >> 5, j = tid & 31;
  float p = 0.f;
  for (int d = j; d < Dc; d += 32) p += xr[d] * rw[e * Dc + d];
  part[e][j] = p;
  __syncthreads();
  if (tid < 8) {
    float s = 0.f;
    for (int q = 0; q < 32; ++q) s += part[tid][q];
    lg[tid] = s;
  }
  __syncthreads();
  if (tid == 0) {
    int i0 = 0;
    for (int q = 1; q < 8; ++q) if (lg[q] > lg[i0]) i0 = q;
    int i1 = (i0 == 0) ? 1 : 0;
    for (int q = 0; q < 8; ++q) if (q != i0 && lg[q] > lg[i1]) i1 = q;
    float mx = lg[0];
    for (int q = 1; q < 8; ++q) mx = fmaxf(mx, lg[q]);
    float ex[8], s = 0.f;
    for (int q = 0; q < 8; ++q) { ex[q] = expf(lg[q] - mx); s += ex[q]; }
    const float inv = 1.f / s;
    float p0v = fminf(fmaxf(ex[i0] * inv + 1e-9f, 1e-9f), 1.f - 1e-9f);
    float p1v = fminf(fmaxf(ex[i1] * inv + 1e-9f, 1e-9f), 1.f - 1e-9f);
    const float sw = 1.f / (p0v + p1v);
    int p0 = atomicAdd(&cnt[i0], 1);
    tok[i0 * Mtok + p0] = row; wt[i0 * Mtok + p0] = p0v * sw;
    int p1 = atomicAdd(&cnt[i1], 1);
    tok[i1 * Mtok + p1] = row; wt[i1 * Mtok + p1] = p1v * sw;
  }
}

// ---------------------------------------------------------------- expert GEMM1: gather -> gelu -> hid
__global__ __launch_bounds__(256) void gemm_e1_kernel(const u16* __restrict__ x2b,
                                                      const u16* __restrict__ w1,
                                                      const int* __restrict__ cnt,
                                                      const int* __restrict__ tok,
                                                      u16* __restrict__ hid) {
  const int bn = blockIdx.x;            // FF/128 = 32
  const int e = blockIdx.y >> 5, it = blockIdx.y & 31;
  const int n_e = cnt[e];
  if (it * 128 >= n_e) return;
  int offs = 0;
  for (int q = 0; q < 8; ++q) offs += (q < e) ? cnt[q] : 0;
  __shared__ u16 As[128 * 32], Bs[128 * 32];
  const int tid = threadIdx.x;
  const int r = tid >> 2, kk = ((tid & 3) ^ (r & 3)) * 8;
  const int i0 = it * 128 + r, i1 = i0 + 64;
  const int t0 = tok[e * Mtok + ((i0 < n_e) ? i0 : (n_e - 1))];
  const int t1 = tok[e * Mtok + ((i1 < n_e) ? i1 : (n_e - 1))];
  const u16* a0 = x2b + (size_t)t0 * 1024 + kk;
  const u16* a1 = x2b + (size_t)t1 * 1024 + kk;
  const u16* b0 = w1 + (size_t)e * FFc * Dc + (size_t)(bn * 128 + r) * 1024 + kk;
  const u16* b1 = b0 + (size_t)64 * 1024;
  f32x4 acc[4][4] = {};
  gemm_f16_core(a0, a1, b0, b1, 1024, As, Bs, acc);
  const int lane = tid & 63, wave = tid >> 6;
  const int wm = (wave & 1) * 64, wn = (wave >> 1) * 64;
  const int col = lane & 15, rb = (lane >> 4) * 4;
#pragma unroll
  for (int mt = 0; mt < 4; ++mt)
#pragma unroll
    for (int rr = 0; rr < 4; ++rr) {
      const int i = it * 128 + wm + mt * 16 + rb + rr;
      if (i < n_e) {
        const size_t hrow = (size_t)(offs + i) * FFc;
#pragma unroll
        for (int nt = 0; nt < 4; ++nt) {
          const int n = bn * 128 + wn + nt * 16 + col;
          hid[hrow + n] = f2h(gelu_f(acc[mt][nt][rr]));
        }
      }
    }
}

// ---------------------------------------------------------------- expert GEMM2: hid x w2^T -> scatter-add
__global__ __launch_bounds__(256) void gemm_e2_kernel(const u16* __restrict__ hid,
                                                      const u16* __restrict__ w2,
                                                      const int* __restrict__ cnt,
                                                      const int* __restrict__ tok,
                                                      const float* __restrict__ wt,
                                                      float* __restrict__ out) {
  const int bn = blockIdx.x;            // D/128 = 8
  const int e = blockIdx.y >> 5, it = blockIdx.y & 31;
  const int n_e = cnt[e];
  if (it * 128 >= n_e) return;
  int offs = 0;
  for (int q = 0; q < 8; ++q) offs += (q < e) ? cnt[q] : 0;
  __shared__ u16 As[128 * 32], Bs[128 * 32];
  const int tid = threadIdx.x;
  const int r = tid >> 2, kk = ((tid & 3) ^ (r & 3)) * 8;
  const int i0 = it * 128 + r, i1 = i0 + 64;
  const int ri0 = offs + ((i0 < n_e) ? i0 : (n_e - 1));
  const int ri1 = offs + ((i1 < n_e) ? i1 : (n_e - 1));
  const u16* a0 = hid + (size_t)ri0 * FFc + kk;
  const u16* a1 = hid + (size_t)ri1 * FFc + kk;
  const u16* b0 = w2 + (size_t)e * Dc * FFc + (size_t)(bn * 128 + r) * FFc + kk;
  const u16* b1 = b0 + (size_t)64 * FFc;
  f32x4 acc[4][4] = {};
  gemm_f16_core(a0, a1, b0, b1, FFc, As, Bs, acc);
  const int lane = tid & 63, wave = tid >> 6;
  const int wm = (wave & 1) * 64, wn = (wave >> 1) * 64;
  const int col = lane & 15, rb = (lane >> 4) * 4;
#pragma unroll
  for (int mt = 0; mt < 4; ++mt)
#pragma unroll
    for (int rr = 0; rr < 4; ++rr) {
      const int i = it * 128 + wm + mt * 16 + rb + rr;
      if (i < n_e) {
        const int tk = tok[e * Mtok + i];
        const float wgt = wt[e * Mtok + i];
#pragma unroll
        for (int nt = 0; nt < 4; ++nt) {
          const int n = bn * 128 + wn + nt * 16 + col;
          atomicAdd(&out[(size_t)tk * 1024 + n], wgt * acc[mt][nt][rr]);
        }
      }
    }
}

// ---------------------------------------------------------------- workspace layout (bytes)
constexpr size_t OFF_WQKV3 = 0;                                       // 2-plane fp16 (12.6MB used)
constexpr size_t OFF_WPROJ3 = 18874368;                               // 2-plane fp16 (4.2MB used)
constexpr size_t OFF_W1 = 25165824;                                   // 67,108,864
constexpr size_t OFF_W2 = 92274688;                                   // 67,108,864
constexpr size_t OFF_HPL = 159383552;                                 // h/o planes (16.8MB used)
constexpr size_t OFF_QKV = 184549376;                                 // 50,331,648 (later hid overlay)
constexpr size_t OFF_OF = 234881024;                                  // 16,777,216
constexpr size_t OFF_X2 = 251658240;                                  //  8,388,608
constexpr size_t OFF_CNT = 260046848;
constexpr size_t OFF_TOK = OFF_CNT + 256;
constexpr size_t OFF_WTL = OFF_TOK + (size_t)Ec * Mtok * 4;

extern "C" void kernel_launch(void* const* d_in, const int* in_sizes, int n_in,
                              void* d_out, int out_size, void* d_ws, size_t ws_size,
                              hipStream_t stream) {
  const float* x = (const float*)d_in[0];
  const float* c = (const float*)d_in[1];
  const float* ln1_w = (const float*)d_in[2];
  const float* w_qkv = (const float*)d_in[3];
  const float* w_proj = (const float*)d_in[4];
  const float* ln2_w = (const float*)d_in[5];
  const float* router_w = (const float*)d_in[6];
  const float* ew1 = (const float*)d_in[7];
  const float* ew2 = (const float*)d_in[8];
  float* out = (float*)d_out;
  char* ws = (char*)d_ws;

  u16* wqkv2 = (u16*)(ws + OFF_WQKV3);
  u16* wproj2 = (u16*)(ws + OFF_WPROJ3);
  u16* w1_h = (u16*)(ws + OFF_W1);
  u16* w2_h = (u16*)(ws + OFF_W2);
  u16* hpl = (u16*)(ws + OFF_HPL);       // h planes, later o planes
  float* qkvf = (float*)(ws + OFF_QKV);
  float* of = (float*)(ws + OFF_OF);     // o fp32, later xmid fp32
  u16* x2_h = (u16*)(ws + OFF_X2);
  u16* hid_h = (u16*)(ws + OFF_QKV);     // overlay (qkv+of dead by expert phase)
  int* cnt = (int*)(ws + OFF_CNT);
  int* tok = (int*)(ws + OFF_TOK);
  float* wtl = (float*)(ws + OFF_WTL);

  // 1) weight conversions (inputs restored every call)
  split2h_kernel<<<(3 * Dc * Dc / 4 + 255) / 256, 256, 0, stream>>>(w_qkv, wqkv2, PS_WQKV, 3 * Dc * Dc / 4);
  split2h_kernel<<<(Dc * Dc / 4 + 255) / 256, 256, 0, stream>>>(w_proj, wproj2, PS_WPROJ, Dc * Dc / 4);
  {
    int n4 = Ec * FFc * Dc / 4;
    cvt_fp16_kernel<<<(n4 + 255) / 256, 256, 0, stream>>>(ew1, w1_h, n4);
    cvt_fp16_kernel<<<(n4 + 255) / 256, 256, 0, stream>>>(ew2, w2_h, n4);
  }
  // 2) h = LN1(x)*w + c -> 2 fp16 planes
  ln1_kernel<<<Mtok, 256, 0, stream>>>(x, ln1_w, c, hpl);
  // 3) qkv = h @ w_qkv^T  (fp16 split-2, fp32 out)
  gemm_qkv_kernel<<<dim3(24, 32), 256, 0, stream>>>(hpl, wqkv2, qkvf);
  // 4) causal attention, bf16 split-2 MFMA flash (64 q rows per block)
  attn_mfma_kernel<<<dim3(Tc / 64, Bc * Hc), 256, 0, stream>>>(qkvf, of);
  // 5) split o -> 2 fp16 planes (h planes dead)
  split2h_kernel<<<(Mtok * Dc / 4 + 255) / 256, 256, 0, stream>>>(of, hpl, PS_H, Mtok * Dc / 4);
  // 6) xmid = x + o @ w_proj^T  (fp16 split-2, fp32 out; overwrites o fp32)
  gemm_proj_kernel<<<dim3(8, 32), 256, 0, stream>>>(hpl, wproj2, x, of);
  // 7) x2 = LN2(xmid): fp32 -> d_out, fp16 -> x2_h
  ln2_kernel<<<Mtok, 256, 0, stream>>>(of, ln2_w, out, x2_h);
  // 8) router -> per-expert token lists
  (void)hipMemsetAsync(cnt, 0, Ec * sizeof(int), stream);
  router_kernel<<<Mtok, 256, 0, stream>>>(out, router_w, cnt, tok, wtl);
  // 9) experts (sparse top-2, fp16 MFMA)
  gemm_e1_kernel<<<dim3(32, 256), 256, 0, stream>>>(x2_h, w1_h, cnt, tok, hid_h);
  gemm_e2_kernel<<<dim3(8, 256), 256, 0, stream>>>(hid_h, w2_h, cnt, tok, wtl, out);
}

// Round 3
// 943.465 us; speedup vs baseline: 1.5620x; 1.0938x over previous
//
#include <hip/hip_runtime.h>
#include <cstdint>
#include <cstddef>

// ---------------------------------------------------------------------------
// NoiseBlockMoE (B=4,T=1024,D=1024,H=16,E=8,top2,FF=4096)
// Round 6: GEMM cores restructured.
//  (a) Bank swizzle fixed: slot ^= (row>>1)&3 (was row&3 -> residual 4-way).
//  (b) Minimal 2-phase pipeline: double-buffered LDS, 1 barrier/k-step,
//      STAGE(next) issued before compute(cur) so DMA latency hides under
//      the MFMA cluster and the syncthreads drain is cheap.
// Attention / LN / router / split kernels unchanged from round 5.
// ---------------------------------------------------------------------------

#define AS1 __attribute__((address_space(1)))
#define AS3 __attribute__((address_space(3)))

typedef unsigned short u16;
typedef __attribute__((ext_vector_type(8))) short short8;     // 8 bf16 = 4 VGPR
typedef __attribute__((ext_vector_type(8))) _Float16 half8;   // 8 fp16 = 4 VGPR
typedef __attribute__((ext_vector_type(4))) float f32x4;

constexpr int Bc = 4, Tc = 1024, Dc = 1024, Hc = 16, Ec = 8, FFc = 4096;
constexpr int Mtok = Bc * Tc;   // 4096 tokens

// plane strides (elements)
constexpr size_t PS_WQKV = (size_t)3 * Dc * Dc;   // 3145728
constexpr size_t PS_WPROJ = (size_t)Dc * Dc;      // 1048576
constexpr size_t PS_H = (size_t)Mtok * Dc;        // 4194304

constexpr float LO_SCALE = 4096.0f;               // 2^12
constexpr float LO_INV = 1.0f / 4096.0f;

__device__ __forceinline__ u16 f2bf(float f) {              // RNE f32->bf16
  unsigned u = __float_as_uint(f);
  u += 0x7fffu + ((u >> 16) & 1u);
  return (u16)(u >> 16);
}
__device__ __forceinline__ float bf2f(u16 v) { return __uint_as_float(((unsigned)v) << 16); }
__device__ __forceinline__ u16 f2h(float f) {               // RNE f32->fp16
  _Float16 h = (_Float16)f;
  return *(u16*)&h;
}
__device__ __forceinline__ float h2f(u16 v) {
  _Float16 h = *(_Float16*)&v;
  return (float)h;
}
__device__ __forceinline__ float gelu_f(float v) {          // exact GELU (erf)
  return 0.5f * v * (1.0f + erff(v * 0.70710678118654752440f));
}

// ---------------------------------------------------------------- cvt f32->fp16 (plain)
__global__ __launch_bounds__(256) void cvt_fp16_kernel(const float* __restrict__ in,
                                                       u16* __restrict__ out, int n4) {
  int i = blockIdx.x * 256 + threadIdx.x;
  if (i >= n4) return;
  float4 v = reinterpret_cast<const float4*>(in)[i];
  uint2 o;
  o.x = (unsigned)f2h(v.x) | ((unsigned)f2h(v.y) << 16);
  o.y = (unsigned)f2h(v.z) | ((unsigned)f2h(v.w) << 16);
  reinterpret_cast<uint2*>(out)[i] = o;
}

// ---------------------------------------------------------------- fp32 -> 2 fp16 planes (lo*2^12)
__global__ __launch_bounds__(256) void split2h_kernel(const float* __restrict__ in,
                                                      u16* __restrict__ out,
                                                      size_t ps, int n4) {
  int i = blockIdx.x * 256 + threadIdx.x;
  if (i >= n4) return;
  float4 v = reinterpret_cast<const float4*>(in)[i];
  float a[4] = {v.x, v.y, v.z, v.w};
  unsigned h[4], lo[4];
#pragma unroll
  for (int j = 0; j < 4; ++j) {
    u16 hh = f2h(a[j]);
    float r = (a[j] - h2f(hh)) * LO_SCALE;
    h[j] = hh; lo[j] = f2h(r);
  }
  uint2 o0, o1;
  o0.x = h[0] | (h[1] << 16);   o0.y = h[2] | (h[3] << 16);
  o1.x = lo[0] | (lo[1] << 16); o1.y = lo[2] | (lo[3] << 16);
  const size_t base = (size_t)i * 4;
  *(uint2*)&out[base] = o0;
  *(uint2*)&out[ps + base] = o1;
}

// ---------------------------------------------------------------- LN1 (+c) -> 2 fp16 planes
__global__ __launch_bounds__(256) void ln1_kernel(const float* __restrict__ x,
                                                  const float* __restrict__ w,
                                                  const float* __restrict__ c,
                                                  u16* __restrict__ hp) {
  const int row = blockIdx.x, tid = threadIdx.x;
  const int b = row >> 10;   // T=1024
  const float4 v = reinterpret_cast<const float4*>(x + (size_t)row * Dc)[tid];
  __shared__ float red[256];
  red[tid] = v.x + v.y + v.z + v.w;
  __syncthreads();
  for (int s = 128; s > 0; s >>= 1) { if (tid < s) red[tid] += red[tid + s]; __syncthreads(); }
  const float mu = red[0] * (1.0f / Dc);
  __syncthreads();
  const float dx = v.x - mu, dy = v.y - mu, dz = v.z - mu, dw = v.w - mu;
  red[tid] = dx * dx + dy * dy + dz * dz + dw * dw;
  __syncthreads();
  for (int s = 128; s > 0; s >>= 1) { if (tid < s) red[tid] += red[tid + s]; __syncthreads(); }
  const float rs = rsqrtf(red[0] * (1.0f / Dc) + 1e-5f);
  const float4 wv = reinterpret_cast<const float4*>(w)[tid];
  const float4 cv = reinterpret_cast<const float4*>(c + (size_t)b * Dc)[tid];
  float a[4];
  a[0] = dx * rs * wv.x + cv.x; a[1] = dy * rs * wv.y + cv.y;
  a[2] = dz * rs * wv.z + cv.z; a[3] = dw * rs * wv.w + cv.w;
  unsigned h[4], lo[4];
#pragma unroll
  for (int j = 0; j < 4; ++j) {
    u16 hh = f2h(a[j]);
    float r = (a[j] - h2f(hh)) * LO_SCALE;
    h[j] = hh; lo[j] = f2h(r);
  }
  uint2 o0, o1;
  o0.x = h[0] | (h[1] << 16);   o0.y = h[2] | (h[3] << 16);
  o1.x = lo[0] | (lo[1] << 16); o1.y = lo[2] | (lo[3] << 16);
  const size_t base = (size_t)row * Dc + tid * 4;
  *(uint2*)&hp[base] = o0;
  *(uint2*)&hp[PS_H + base] = o1;
}

// ---------------------------------------------------------------- LN2 -> f32 (d_out) + fp16
__global__ __launch_bounds__(256) void ln2_kernel(const float* __restrict__ xin,
                                                  const float* __restrict__ w,
                                                  float* __restrict__ xf,
                                                  u16* __restrict__ xb) {
  const int row = blockIdx.x, tid = threadIdx.x;
  const float4 v = reinterpret_cast<const float4*>(xin + (size_t)row * Dc)[tid];
  __shared__ float red[256];
  red[tid] = v.x + v.y + v.z + v.w;
  __syncthreads();
  for (int s = 128; s > 0; s >>= 1) { if (tid < s) red[tid] += red[tid + s]; __syncthreads(); }
  const float mu = red[0] * (1.0f / Dc);
  __syncthreads();
  const float dx = v.x - mu, dy = v.y - mu, dz = v.z - mu, dw = v.w - mu;
  red[tid] = dx * dx + dy * dy + dz * dz + dw * dw;
  __syncthreads();
  for (int s = 128; s > 0; s >>= 1) { if (tid < s) red[tid] += red[tid + s]; __syncthreads(); }
  const float rs = rsqrtf(red[0] * (1.0f / Dc) + 1e-5f);
  const float4 wv = reinterpret_cast<const float4*>(w)[tid];
  float4 ov;
  ov.x = dx * rs * wv.x; ov.y = dy * rs * wv.y; ov.z = dz * rs * wv.z; ov.w = dw * rs * wv.w;
  reinterpret_cast<float4*>(xf + (size_t)row * Dc)[tid] = ov;
  uint2 o;
  o.x = (unsigned)f2h(ov.x) | ((unsigned)f2h(ov.y) << 16);
  o.y = (unsigned)f2h(ov.z) | ((unsigned)f2h(ov.w) << 16);
  reinterpret_cast<uint2*>(xb + (size_t)row * Dc)[tid] = o;
}

// ---------------------------------------------------------------- staging helpers
__device__ __forceinline__ void stage4(const u16* a0, const u16* a1,
                                       const u16* b0, const u16* b1,
                                       u16* buf, int lds0) {
  __builtin_amdgcn_global_load_lds((AS1 void*)a0, (AS3 void*)(buf + lds0), 16, 0, 0);
  __builtin_amdgcn_global_load_lds((AS1 void*)a1, (AS3 void*)(buf + 2048 + lds0), 16, 0, 0);
  __builtin_amdgcn_global_load_lds((AS1 void*)b0, (AS3 void*)(buf + 4096 + lds0), 16, 0, 0);
  __builtin_amdgcn_global_load_lds((AS1 void*)b1, (AS3 void*)(buf + 6144 + lds0), 16, 0, 0);
}
__device__ __forceinline__ void stage8(const u16* ah0, const u16* ah1,
                                       const u16* al0, const u16* al1,
                                       const u16* bh0, const u16* bh1,
                                       const u16* bl0, const u16* bl1,
                                       u16* buf, int lds0) {
  __builtin_amdgcn_global_load_lds((AS1 void*)ah0, (AS3 void*)(buf + lds0), 16, 0, 0);
  __builtin_amdgcn_global_load_lds((AS1 void*)ah1, (AS3 void*)(buf + 2048 + lds0), 16, 0, 0);
  __builtin_amdgcn_global_load_lds((AS1 void*)al0, (AS3 void*)(buf + 4096 + lds0), 16, 0, 0);
  __builtin_amdgcn_global_load_lds((AS1 void*)al1, (AS3 void*)(buf + 6144 + lds0), 16, 0, 0);
  __builtin_amdgcn_global_load_lds((AS1 void*)bh0, (AS3 void*)(buf + 8192 + lds0), 16, 0, 0);
  __builtin_amdgcn_global_load_lds((AS1 void*)bh1, (AS3 void*)(buf + 10240 + lds0), 16, 0, 0);
  __builtin_amdgcn_global_load_lds((AS1 void*)bl0, (AS3 void*)(buf + 12288 + lds0), 16, 0, 0);
  __builtin_amdgcn_global_load_lds((AS1 void*)bl1, (AS3 void*)(buf + 14336 + lds0), 16, 0, 0);
}

// ---------------------------------------------------------------- fp16 GEMM core (single plane)
// Double-buffered, 1 barrier per k-step. LDS buffer layout (u16 offsets):
// A rows 0-63 @0, rows 64-127 @2048, B rows 0-63 @4096, rows 64-127 @6144.
// Bank swizzle: 16B slot ^= (row>>1)&3, source-permuted at staging
// (caller passes kk = ((tid&3) ^ ((r>>1)&3))*8).
__device__ __forceinline__ void gemm_f16_core(const u16* a0, const u16* a1,
                                              const u16* b0, const u16* b1,
                                              int K, u16* S, f32x4 acc[4][4]) {
  const int tid = threadIdx.x;
  const int lane = tid & 63;
  const int wave = tid >> 6;
  const int wm = (wave & 1) * 64;
  const int wn = (wave >> 1) * 64;
  const int frow = lane & 15;
  const int gs = ((lane >> 4) ^ ((frow >> 1) & 3)) * 8;   // swizzled 16B slot
  int aoff[4], boff[4];
#pragma unroll
  for (int t = 0; t < 4; ++t) {
    aoff[t] = (wm + t * 16 + frow) * 32 + gs;
    boff[t] = 4096 + (wn + t * 16 + frow) * 32 + gs;
  }
  const int lds0 = tid * 8;
  stage4(a0, a1, b0, b1, S, lds0);
  a0 += 32; a1 += 32; b0 += 32; b1 += 32;
  int cur = 0;
  for (int k0 = 0; k0 < K; k0 += 32) {
    __syncthreads();                       // buf[cur] staged; prior reads of buf[cur^1] done
    if (k0 + 32 < K) {
      stage4(a0, a1, b0, b1, S + (cur ^ 1) * 8192, lds0);
      a0 += 32; a1 += 32; b0 += 32; b1 += 32;
    }
    const u16* As = S + cur * 8192;
    half8 af[4], bfr[4];
#pragma unroll
    for (int t = 0; t < 4; ++t) af[t] = *(const half8*)(As + aoff[t]);
#pragma unroll
    for (int t = 0; t < 4; ++t) bfr[t] = *(const half8*)(As + boff[t]);
#pragma unroll
    for (int mt = 0; mt < 4; ++mt)
#pragma unroll
      for (int nt = 0; nt < 4; ++nt)
        acc[mt][nt] = __builtin_amdgcn_mfma_f32_16x16x32_f16(af[mt], bfr[nt], acc[mt][nt], 0, 0, 0);
    cur ^= 1;
  }
}

// ---------------------------------------------------------------- fp16 split-2 core, shared staging
// Buffer layout (u16): Ah@0, Al@4096, Bh@8192, Bl@12288 (each plane 2 halves).
// Double-buffered (2 x 32KB), 1 barrier per k-step, 48 MFMA per step.
__device__ __forceinline__ void gemm_f16s2_core(const u16* ah0, const u16* ah1,
                                                const u16* al0, const u16* al1,
                                                const u16* bh0, const u16* bh1,
                                                const u16* bl0, const u16* bl1,
                                                int K, u16* S,
                                                f32x4 acc0[4][4], f32x4 acc1[4][4]) {
  const int tid = threadIdx.x;
  const int lane = tid & 63;
  const int wave = tid >> 6;
  const int wm = (wave & 1) * 64;
  const int wn = (wave >> 1) * 64;
  const int frow = lane & 15;
  const int gs = ((lane >> 4) ^ ((frow >> 1) & 3)) * 8;
  int aoff[4], boff[4];
#pragma unroll
  for (int t = 0; t < 4; ++t) {
    aoff[t] = (wm + t * 16 + frow) * 32 + gs;
    boff[t] = 8192 + (wn + t * 16 + frow) * 32 + gs;
  }
  const int lds0 = tid * 8;
  stage8(ah0, ah1, al0, al1, bh0, bh1, bl0, bl1, S, lds0);
  ah0 += 32; ah1 += 32; al0 += 32; al1 += 32;
  bh0 += 32; bh1 += 32; bl0 += 32; bl1 += 32;
  int cur = 0;
  for (int k0 = 0; k0 < K; k0 += 32) {
    __syncthreads();
    if (k0 + 32 < K) {
      stage8(ah0, ah1, al0, al1, bh0, bh1, bl0, bl1, S + (cur ^ 1) * 16384, lds0);
      ah0 += 32; ah1 += 32; al0 += 32; al1 += 32;
      bh0 += 32; bh1 += 32; bl0 += 32; bl1 += 32;
    }
    const u16* Sb = S + cur * 16384;
    half8 ahf[4], bhf[4];
#pragma unroll
    for (int t = 0; t < 4; ++t) {
      ahf[t] = *(const half8*)(Sb + aoff[t]);
      bhf[t] = *(const half8*)(Sb + boff[t]);
    }
#pragma unroll
    for (int mt = 0; mt < 4; ++mt)
#pragma unroll
      for (int nt = 0; nt < 4; ++nt)
        acc0[mt][nt] = __builtin_amdgcn_mfma_f32_16x16x32_f16(ahf[mt], bhf[nt], acc0[mt][nt], 0, 0, 0);
    {
      half8 alf[4];
#pragma unroll
      for (int t = 0; t < 4; ++t) alf[t] = *(const half8*)(Sb + 4096 + aoff[t]);
#pragma unroll
      for (int mt = 0; mt < 4; ++mt)
#pragma unroll
        for (int nt = 0; nt < 4; ++nt)
          acc1[mt][nt] = __builtin_amdgcn_mfma_f32_16x16x32_f16(alf[mt], bhf[nt], acc1[mt][nt], 0, 0, 0);
    }
    {
      half8 blf[4];
#pragma unroll
      for (int t = 0; t < 4; ++t) blf[t] = *(const half8*)(Sb + 4096 + boff[t]);
#pragma unroll
      for (int mt = 0; mt < 4; ++mt)
#pragma unroll
        for (int nt = 0; nt < 4; ++nt)
          acc1[mt][nt] = __builtin_amdgcn_mfma_f32_16x16x32_f16(ahf[mt], blf[nt], acc1[mt][nt], 0, 0, 0);
    }
    cur ^= 1;
  }
}

// ---------------------------------------------------------------- qkv split-2 GEMM -> fp32
__global__ __launch_bounds__(256) void gemm_qkv_kernel(const u16* __restrict__ A,
                                                       const u16* __restrict__ Bw,
                                                       float* __restrict__ Cout) {
  __shared__ u16 S[2 * 16384];   // 64KB double buffer
  const int bn = blockIdx.x, bm = blockIdx.y, tid = threadIdx.x;
  const int r = tid >> 2, kk = ((tid & 3) ^ ((r >> 1) & 3)) * 8;
  const u16* ah0 = A + (size_t)(bm * 128 + r) * 1024 + kk;
  const u16* ah1 = ah0 + (size_t)64 * 1024;
  const u16* bh0 = Bw + (size_t)(bn * 128 + r) * 1024 + kk;
  const u16* bh1 = bh0 + (size_t)64 * 1024;
  f32x4 acc0[4][4] = {}, acc1[4][4] = {};
  gemm_f16s2_core(ah0, ah1, ah0 + PS_H, ah1 + PS_H,
                  bh0, bh1, bh0 + PS_WQKV, bh1 + PS_WQKV,
                  1024, S, acc0, acc1);
  const int lane = tid & 63, wave = tid >> 6;
  const int wm = (wave & 1) * 64, wn = (wave >> 1) * 64;
  const int col = lane & 15, rb = (lane >> 4) * 4;
#pragma unroll
  for (int mt = 0; mt < 4; ++mt)
#pragma unroll
    for (int rr = 0; rr < 4; ++rr) {
      const int m = bm * 128 + wm + mt * 16 + rb + rr;
#pragma unroll
      for (int nt = 0; nt < 4; ++nt) {
        const int n = bn * 128 + wn + nt * 16 + col;
        Cout[(size_t)m * 3072 + n] = acc0[mt][nt][rr] + acc1[mt][nt][rr] * LO_INV;
      }
    }
}

// ---------------------------------------------------------------- proj split-2 GEMM + residual -> fp32
__global__ __launch_bounds__(256) void gemm_proj_kernel(const u16* __restrict__ A,
                                                        const u16* __restrict__ Bw,
                                                        const float* __restrict__ xres,
                                                        float* __restrict__ xmid) {
  __shared__ u16 S[2 * 16384];   // 64KB double buffer
  const int bn = blockIdx.x, bm = blockIdx.y, tid = threadIdx.x;
  const int r = tid >> 2, kk = ((tid & 3) ^ ((r >> 1) & 3)) * 8;
  const u16* ah0 = A + (size_t)(bm * 128 + r) * 1024 + kk;
  const u16* ah1 = ah0 + (size_t)64 * 1024;
  const u16* bh0 = Bw + (size_t)(bn * 128 + r) * 1024 + kk;
  const u16* bh1 = bh0 + (size_t)64 * 1024;
  f32x4 acc0[4][4] = {}, acc1[4][4] = {};
  gemm_f16s2_core(ah0, ah1, ah0 + PS_H, ah1 + PS_H,
                  bh0, bh1, bh0 + PS_WPROJ, bh1 + PS_WPROJ,
                  1024, S, acc0, acc1);
  const int lane = tid & 63, wave = tid >> 6;
  const int wm = (wave & 1) * 64, wn = (wave >> 1) * 64;
  const int col = lane & 15, rb = (lane >> 4) * 4;
#pragma unroll
  for (int mt = 0; mt < 4; ++mt)
#pragma unroll
    for (int rr = 0; rr < 4; ++rr) {
      const int m = bm * 128 + wm + mt * 16 + rb + rr;
#pragma unroll
      for (int nt = 0; nt < 4; ++nt) {
        const int n = bn * 128 + wn + nt * 16 + col;
        xmid[(size_t)m * 1024 + n] =
            xres[(size_t)m * 1024 + n] + acc0[mt][nt][rr] + acc1[mt][nt][rr] * LO_INV;
      }
    }
}

// ---------------------------------------------------------------- attention, bf16 split-2 MFMA flash
// (unchanged from round 4)
__global__ __launch_bounds__(256, 3) void attn_mfma_kernel(const float* __restrict__ qkv,
                                                           float* __restrict__ obuf) {
  constexpr int KS = 72;    // K/V row stride (u16)
  constexpr int PSt = 68;   // P row stride (u16)
  __shared__ u16 Kh[64 * KS], Klo[64 * KS];
  __shared__ u16 Vh[64 * KS], Vlo[64 * KS];
  __shared__ u16 Ph[4][16 * PSt], Pl[4][16 * PSt];

  const int tid = threadIdx.x, lane = tid & 63, w = tid >> 6;
  const int lr = lane & 15, g = lane >> 4;
  const int bh = blockIdx.y, b = bh >> 4, h = bh & 15;
  const int blk = blockIdx.x;
  const int qrow = blk * 64 + w * 16 + lr;

  short8 qh[2], ql[2];
  {
    const float* qp = qkv + (size_t)(b * Tc + qrow) * 3072 + h * 64 + g * 8;
    const float4 f0 = *(const float4*)(qp);
    const float4 f1 = *(const float4*)(qp + 4);
    const float4 f2 = *(const float4*)(qp + 32);
    const float4 f3 = *(const float4*)(qp + 36);
    const float qq[16] = {f0.x, f0.y, f0.z, f0.w, f1.x, f1.y, f1.z, f1.w,
                          f2.x, f2.y, f2.z, f2.w, f3.x, f3.y, f3.z, f3.w};
#pragma unroll
    for (int s = 0; s < 2; ++s)
#pragma unroll
      for (int j = 0; j < 8; ++j) {
        const float v = qq[s * 8 + j] * 0.125f;
        const u16 hi = f2bf(v);
        qh[s][j] = (short)hi;
        ql[s][j] = (short)f2bf(v - bf2f(hi));
      }
  }

  const int tkl = (tid & 31) * 2;
  const int td0 = (tid >> 5) * 8;
  const float* kgb = qkv + (size_t)b * Tc * 3072 + 1024 + h * 64;
  const float* vgb = kgb + 1024;

  f32x4 oacc[4] = {};
  float mrun = -1e30f, lrun = 0.f;

  for (int c = 0; c <= blk; ++c) {
    const int k0 = c * 64;
    __syncthreads();
    {
      const float* kr0 = kgb + (size_t)(k0 + tkl) * 3072 + td0;
      const float* kr1 = kr0 + 3072;
      const float* vr0 = vgb + (size_t)(k0 + tkl) * 3072 + td0;
      const float* vr1 = vr0 + 3072;
      const float4 ka0 = *(const float4*)kr0, ka1 = *(const float4*)(kr0 + 4);
      const float4 kb0 = *(const float4*)kr1, kb1 = *(const float4*)(kr1 + 4);
      const float4 va0 = *(const float4*)vr0, va1 = *(const float4*)(vr0 + 4);
      const float4 vb0 = *(const float4*)vr1, vb1 = *(const float4*)(vr1 + 4);
      const float ka[8] = {ka0.x, ka0.y, ka0.z, ka0.w, ka1.x, ka1.y, ka1.z, ka1.w};
      const float kb[8] = {kb0.x, kb0.y, kb0.z, kb0.w, kb1.x, kb1.y, kb1.z, kb1.w};
      const float va[8] = {va0.x, va0.y, va0.z, va0.w, va1.x, va1.y, va1.z, va1.w};
      const float vb[8] = {vb0.x, vb0.y, vb0.z, vb0.w, vb1.x, vb1.y, vb1.z, vb1.w};
      short8 kh0, kl0, kh1, kl1;
#pragma unroll
      for (int j = 0; j < 8; ++j) {
        const u16 h0 = f2bf(ka[j]); kh0[j] = (short)h0; kl0[j] = (short)f2bf(ka[j] - bf2f(h0));
        const u16 h1 = f2bf(kb[j]); kh1[j] = (short)h1; kl1[j] = (short)f2bf(kb[j] - bf2f(h1));
      }
      *(short8*)(Kh + tkl * KS + td0) = kh0;
      *(short8*)(Kh + (tkl + 1) * KS + td0) = kh1;
      *(short8*)(Klo + tkl * KS + td0) = kl0;
      *(short8*)(Klo + (tkl + 1) * KS + td0) = kl1;
#pragma unroll
      for (int i = 0; i < 8; ++i) {
        const u16 h0 = f2bf(va[i]); const u16 l0 = f2bf(va[i] - bf2f(h0));
        const u16 h1 = f2bf(vb[i]); const u16 l1 = f2bf(vb[i] - bf2f(h1));
        *(unsigned*)(Vh + (td0 + i) * KS + tkl) = (unsigned)h0 | ((unsigned)h1 << 16);
        *(unsigned*)(Vlo + (td0 + i) * KS + tkl) = (unsigned)l0 | ((unsigned)l1 << 16);
      }
    }
    __syncthreads();

    f32x4 sacc[4] = {};
#pragma unroll
    for (int kt = 0; kt < 4; ++kt) {
      const u16* kap = Kh + (kt * 16 + lr) * KS + g * 8;
      const u16* klp = Klo + (kt * 16 + lr) * KS + g * 8;
      const short8 ah0 = *(const short8*)kap;
      const short8 ah1 = *(const short8*)(kap + 32);
      const short8 al0 = *(const short8*)klp;
      const short8 al1 = *(const short8*)(klp + 32);
      sacc[kt] = __builtin_amdgcn_mfma_f32_16x16x32_bf16(ah0, qh[0], sacc[kt], 0, 0, 0);
      sacc[kt] = __builtin_amdgcn_mfma_f32_16x16x32_bf16(al0, qh[0], sacc[kt], 0, 0, 0);
      sacc[kt] = __builtin_amdgcn_mfma_f32_16x16x32_bf16(ah0, ql[0], sacc[kt], 0, 0, 0);
      sacc[kt] = __builtin_amdgcn_mfma_f32_16x16x32_bf16(ah1, qh[1], sacc[kt], 0, 0, 0);
      sacc[kt] = __builtin_amdgcn_mfma_f32_16x16x32_bf16(al1, qh[1], sacc[kt], 0, 0, 0);
      sacc[kt] = __builtin_amdgcn_mfma_f32_16x16x32_bf16(ah1, ql[1], sacc[kt], 0, 0, 0);
    }

    if (c == blk) {
#pragma unroll
      for (int kt = 0; kt < 4; ++kt)
#pragma unroll
        for (int r = 0; r < 4; ++r)
          if (k0 + kt * 16 + g * 4 + r > qrow) sacc[kt][r] = -1e30f;
    }

    float mt = -1e30f;
#pragma unroll
    for (int kt = 0; kt < 4; ++kt)
#pragma unroll
      for (int r = 0; r < 4; ++r) mt = fmaxf(mt, sacc[kt][r]);
    mt = fmaxf(mt, __shfl_xor(mt, 16));
    mt = fmaxf(mt, __shfl_xor(mt, 32));
    const float mnew = fmaxf(mrun, mt);
    const float alpha = __expf(mrun - mnew);
    float psum = 0.f;
    u16* php = Ph[w] + lr * PSt;
    u16* plp = Pl[w] + lr * PSt;
#pragma unroll
    for (int kt = 0; kt < 4; ++kt) {
      u16 hh[4], ll[4];
#pragma unroll
      for (int r = 0; r < 4; ++r) {
        const float p = __expf(sacc[kt][r] - mnew);
        psum += p;
        hh[r] = f2bf(p);
        ll[r] = f2bf(p - bf2f(hh[r]));
      }
      uint2 wh, wl;
      wh.x = (unsigned)hh[0] | ((unsigned)hh[1] << 16);
      wh.y = (unsigned)hh[2] | ((unsigned)hh[3] << 16);
      wl.x = (unsigned)ll[0] | ((unsigned)ll[1] << 16);
      wl.y = (unsigned)ll[2] | ((unsigned)ll[3] << 16);
      *(uint2*)(php + kt * 16 + g * 4) = wh;
      *(uint2*)(plp + kt * 16 + g * 4) = wl;
    }
    psum += __shfl_xor(psum, 16);
    psum += __shfl_xor(psum, 32);
    mrun = mnew;
    lrun = lrun * alpha + psum;
#pragma unroll
    for (int dt = 0; dt < 4; ++dt) {
      oacc[dt][0] *= alpha; oacc[dt][1] *= alpha;
      oacc[dt][2] *= alpha; oacc[dt][3] *= alpha;
    }
    __syncthreads();

    const short8 pbh0 = *(const short8*)(php + g * 8);
    const short8 pbh1 = *(const short8*)(php + 32 + g * 8);
    const short8 pbl0 = *(const short8*)(plp + g * 8);
    const short8 pbl1 = *(const short8*)(plp + 32 + g * 8);
#pragma unroll
    for (int dt = 0; dt < 4; ++dt) {
      const u16* vap = Vh + (dt * 16 + lr) * KS + g * 8;
      const u16* vlp2 = Vlo + (dt * 16 + lr) * KS + g * 8;
      const short8 vh0 = *(const short8*)vap;
      const short8 vh1 = *(const short8*)(vap + 32);
      const short8 vl0 = *(const short8*)vlp2;
      const short8 vl1 = *(const short8*)(vlp2 + 32);
      oacc[dt] = __builtin_amdgcn_mfma_f32_16x16x32_bf16(vh0, pbh0, oacc[dt], 0, 0, 0);
      oacc[dt] = __builtin_amdgcn_mfma_f32_16x16x32_bf16(vl0, pbh0, oacc[dt], 0, 0, 0);
      oacc[dt] = __builtin_amdgcn_mfma_f32_16x16x32_bf16(vh0, pbl0, oacc[dt], 0, 0, 0);
      oacc[dt] = __builtin_amdgcn_mfma_f32_16x16x32_bf16(vh1, pbh1, oacc[dt], 0, 0, 0);
      oacc[dt] = __builtin_amdgcn_mfma_f32_16x16x32_bf16(vl1, pbh1, oacc[dt], 0, 0, 0);
      oacc[dt] = __builtin_amdgcn_mfma_f32_16x16x32_bf16(vh1, pbl1, oacc[dt], 0, 0, 0);
    }
  }

  const float invl = 1.0f / lrun;
  float* ob = obuf + (size_t)(b * Tc + qrow) * 1024 + h * 64;
#pragma unroll
  for (int dt = 0; dt < 4; ++dt) {
    float4 o4;
    o4.x = oacc[dt][0] * invl; o4.y = oacc[dt][1] * invl;
    o4.z = oacc[dt][2] * invl; o4.w = oacc[dt][3] * invl;
    *(float4*)(ob + dt * 16 + g * 4) = o4;
  }
}

// ---------------------------------------------------------------- router (fp32) + top-2 append
__global__ __launch_bounds__(256) void router_kernel(const float* __restrict__ x2,
                                                     const float* __restrict__ rw,
                                                     int* __restrict__ cnt,
                                                     int* __restrict__ tok,
                                                     float* __restrict__ wt) {
  __shared__ float xr[1024];
  __shared__ float part[8][32];
  __shared__ float lg[8];
  const int row = blockIdx.x, tid = threadIdx.x;
  reinterpret_cast<float4*>(xr)[tid] = reinterpret_cast<const float4*>(x2 + (size_t)row * Dc)[tid];
  __syncthreads();
  const int e = tid >> 5, j = tid & 31;
  float p = 0.f;
  for (int d = j; d < Dc; d += 32) p += xr[d] * rw[e * Dc + d];
  part[e][j] = p;
  __syncthreads();
  if (tid < 8) {
    float s = 0.f;
    for (int q = 0; q < 32; ++q) s += part[tid][q];
    lg[tid] = s;
  }
  __syncthreads();
  if (tid == 0) {
    int i0 = 0;
    for (int q = 1; q < 8; ++q) if (lg[q] > lg[i0]) i0 = q;
    int i1 = (i0 == 0) ? 1 : 0;
    for (int q = 0; q < 8; ++q) if (q != i0 && lg[q] > lg[i1]) i1 = q;
    float mx = lg[0];
    for (int q = 1; q < 8; ++q) mx = fmaxf(mx, lg[q]);
    float ex[8], s = 0.f;
    for (int q = 0; q < 8; ++q) { ex[q] = expf(lg[q] - mx); s += ex[q]; }
    const float inv = 1.f / s;
    float p0v = fminf(fmaxf(ex[i0] * inv + 1e-9f, 1e-9f), 1.f - 1e-9f);
    float p1v = fminf(fmaxf(ex[i1] * inv + 1e-9f, 1e-9f), 1.f - 1e-9f);
    const float sw = 1.f / (p0v + p1v);
    int p0 = atomicAdd(&cnt[i0], 1);
    tok[i0 * Mtok + p0] = row; wt[i0 * Mtok + p0] = p0v * sw;
    int p1 = atomicAdd(&cnt[i1], 1);
    tok[i1 * Mtok + p1] = row; wt[i1 * Mtok + p1] = p1v * sw;
  }
}

// ---------------------------------------------------------------- expert GEMM1: gather -> gelu -> hid
__global__ __launch_bounds__(256) void gemm_e1_kernel(const u16* __restrict__ x2b,
                                                      const u16* __restrict__ w1,
                                                      const int* __restrict__ cnt,
                                                      const int* __restrict__ tok,
                                                      u16* __restrict__ hid) {
  const int bn = blockIdx.x;            // FF/128 = 32
  const int e = blockIdx.y >> 5, it = blockIdx.y & 31;
  const int n_e = cnt[e];
  if (it * 128 >= n_e) return;
  int offs = 0;
  for (int q = 0; q < 8; ++q) offs += (q < e) ? cnt[q] : 0;
  __shared__ u16 S[2 * 8192];   // 32KB double buffer
  const int tid = threadIdx.x;
  const int r = tid >> 2, kk = ((tid & 3) ^ ((r >> 1) & 3)) * 8;
  const int i0 = it * 128 + r, i1 = i0 + 64;
  const int t0 = tok[e * Mtok + ((i0 < n_e) ? i0 : (n_e - 1))];
  const int t1 = tok[e * Mtok + ((i1 < n_e) ? i1 : (n_e - 1))];
  const u16* a0 = x2b + (size_t)t0 * 1024 + kk;
  const u16* a1 = x2b + (size_t)t1 * 1024 + kk;
  const u16* b0 = w1 + (size_t)e * FFc * Dc + (size_t)(bn * 128 + r) * 1024 + kk;
  const u16* b1 = b0 + (size_t)64 * 1024;
  f32x4 acc[4][4] = {};
  gemm_f16_core(a0, a1, b0, b1, 1024, S, acc);
  const int lane = tid & 63, wave = tid >> 6;
  const int wm = (wave & 1) * 64, wn = (wave >> 1) * 64;
  const int col = lane & 15, rb = (lane >> 4) * 4;
#pragma unroll
  for (int mt = 0; mt < 4; ++mt)
#pragma unroll
    for (int rr = 0; rr < 4; ++rr) {
      const int i = it * 128 + wm + mt * 16 + rb + rr;
      if (i < n_e) {
        const size_t hrow = (size_t)(offs + i) * FFc;
#pragma unroll
        for (int nt = 0; nt < 4; ++nt) {
          const int n = bn * 128 + wn + nt * 16 + col;
          hid[hrow + n] = f2h(gelu_f(acc[mt][nt][rr]));
        }
      }
    }
}

// ---------------------------------------------------------------- expert GEMM2: hid x w2^T -> scatter-add
__global__ __launch_bounds__(256) void gemm_e2_kernel(const u16* __restrict__ hid,
                                                      const u16* __restrict__ w2,
                                                      const int* __restrict__ cnt,
                                                      const int* __restrict__ tok,
                                                      const float* __restrict__ wt,
                                                      float* __restrict__ out) {
  const int bn = blockIdx.x;            // D/128 = 8
  const int e = blockIdx.y >> 5, it = blockIdx.y & 31;
  const int n_e = cnt[e];
  if (it * 128 >= n_e) return;
  int offs = 0;
  for (int q = 0; q < 8; ++q) offs += (q < e) ? cnt[q] : 0;
  __shared__ u16 S[2 * 8192];   // 32KB double buffer
  const int tid = threadIdx.x;
  const int r = tid >> 2, kk = ((tid & 3) ^ ((r >> 1) & 3)) * 8;
  const int i0 = it * 128 + r, i1 = i0 + 64;
  const int ri0 = offs + ((i0 < n_e) ? i0 : (n_e - 1));
  const int ri1 = offs + ((i1 < n_e) ? i1 : (n_e - 1));
  const u16* a0 = hid + (size_t)ri0 * FFc + kk;
  const u16* a1 = hid + (size_t)ri1 * FFc + kk;
  const u16* b0 = w2 + (size_t)e * Dc * FFc + (size_t)(bn * 128 + r) * FFc + kk;
  const u16* b1 = b0 + (size_t)64 * FFc;
  f32x4 acc[4][4] = {};
  gemm_f16_core(a0, a1, b0, b1, FFc, S, acc);
  const int lane = tid & 63, wave = tid >> 6;
  const int wm = (wave & 1) * 64, wn = (wave >> 1) * 64;
  const int col = lane & 15, rb = (lane >> 4) * 4;
#pragma unroll
  for (int mt = 0; mt < 4; ++mt)
#pragma unroll
    for (int rr = 0; rr < 4; ++rr) {
      const int i = it * 128 + wm + mt * 16 + rb + rr;
      if (i < n_e) {
        const int tk = tok[e * Mtok + i];
        const float wgt = wt[e * Mtok + i];
#pragma unroll
        for (int nt = 0; nt < 4; ++nt) {
          const int n = bn * 128 + wn + nt * 16 + col;
          atomicAdd(&out[(size_t)tk * 1024 + n], wgt * acc[mt][nt][rr]);
        }
      }
    }
}

// ---------------------------------------------------------------- workspace layout (bytes)
constexpr size_t OFF_WQKV3 = 0;                                       // 2-plane fp16 (12.6MB used)
constexpr size_t OFF_WPROJ3 = 18874368;                               // 2-plane fp16 (4.2MB used)
constexpr size_t OFF_W1 = 25165824;                                   // 67,108,864
constexpr size_t OFF_W2 = 92274688;                                   // 67,108,864
constexpr size_t OFF_HPL = 159383552;                                 // h/o planes (16.8MB used)
constexpr size_t OFF_QKV = 184549376;                                 // 50,331,648 (later hid overlay)
constexpr size_t OFF_OF = 234881024;                                  // 16,777,216
constexpr size_t OFF_X2 = 251658240;                                  //  8,388,608
constexpr size_t OFF_CNT = 260046848;
constexpr size_t OFF_TOK = OFF_CNT + 256;
constexpr size_t OFF_WTL = OFF_TOK + (size_t)Ec * Mtok * 4;

extern "C" void kernel_launch(void* const* d_in, const int* in_sizes, int n_in,
                              void* d_out, int out_size, void* d_ws, size_t ws_size,
                              hipStream_t stream) {
  const float* x = (const float*)d_in[0];
  const float* c = (const float*)d_in[1];
  const float* ln1_w = (const float*)d_in[2];
  const float* w_qkv = (const float*)d_in[3];
  const float* w_proj = (const float*)d_in[4];
  const float* ln2_w = (const float*)d_in[5];
  const float* router_w = (const float*)d_in[6];
  const float* ew1 = (const float*)d_in[7];
  const float* ew2 = (const float*)d_in[8];
  float* out = (float*)d_out;
  char* ws = (char*)d_ws;

  u16* wqkv2 = (u16*)(ws + OFF_WQKV3);
  u16* wproj2 = (u16*)(ws + OFF_WPROJ3);
  u16* w1_h = (u16*)(ws + OFF_W1);
  u16* w2_h = (u16*)(ws + OFF_W2);
  u16* hpl = (u16*)(ws + OFF_HPL);       // h planes, later o planes
  float* qkvf = (float*)(ws + OFF_QKV);
  float* of = (float*)(ws + OFF_OF);     // o fp32, later xmid fp32
  u16* x2_h = (u16*)(ws + OFF_X2);
  u16* hid_h = (u16*)(ws + OFF_QKV);     // overlay (qkv+of dead by expert phase)
  int* cnt = (int*)(ws + OFF_CNT);
  int* tok = (int*)(ws + OFF_TOK);
  float* wtl = (float*)(ws + OFF_WTL);

  // 1) weight conversions (inputs restored every call)
  split2h_kernel<<<(3 * Dc * Dc / 4 + 255) / 256, 256, 0, stream>>>(w_qkv, wqkv2, PS_WQKV, 3 * Dc * Dc / 4);
  split2h_kernel<<<(Dc * Dc / 4 + 255) / 256, 256, 0, stream>>>(w_proj, wproj2, PS_WPROJ, Dc * Dc / 4);
  {
    int n4 = Ec * FFc * Dc / 4;
    cvt_fp16_kernel<<<(n4 + 255) / 256, 256, 0, stream>>>(ew1, w1_h, n4);
    cvt_fp16_kernel<<<(n4 + 255) / 256, 256, 0, stream>>>(ew2, w2_h, n4);
  }
  // 2) h = LN1(x)*w + c -> 2 fp16 planes
  ln1_kernel<<<Mtok, 256, 0, stream>>>(x, ln1_w, c, hpl);
  // 3) qkv = h @ w_qkv^T  (fp16 split-2, fp32 out)
  gemm_qkv_kernel<<<dim3(24, 32), 256, 0, stream>>>(hpl, wqkv2, qkvf);
  // 4) causal attention, bf16 split-2 MFMA flash (64 q rows per block)
  attn_mfma_kernel<<<dim3(Tc / 64, Bc * Hc), 256, 0, stream>>>(qkvf, of);
  // 5) split o -> 2 fp16 planes (h planes dead)
  split2h_kernel<<<(Mtok * Dc / 4 + 255) / 256, 256, 0, stream>>>(of, hpl, PS_H, Mtok * Dc / 4);
  // 6) xmid = x + o @ w_proj^T  (fp16 split-2, fp32 out; overwrites o fp32)
  gemm_proj_kernel<<<dim3(8, 32), 256, 0, stream>>>(hpl, wproj2, x, of);
  // 7) x2 = LN2(xmid): fp32 -> d_out, fp16 -> x2_h
  ln2_kernel<<<Mtok, 256, 0, stream>>>(of, ln2_w, out, x2_h);
  // 8) router -> per-expert token lists
  (void)hipMemsetAsync(cnt, 0, Ec * sizeof(int), stream);
  router_kernel<<<Mtok, 256, 0, stream>>>(out, router_w, cnt, tok, wtl);
  // 9) experts (sparse top-2, fp16 MFMA)
  gemm_e1_kernel<<<dim3(32, 256), 256, 0, stream>>>(x2_h, w1_h, cnt, tok, hid_h);
  gemm_e2_kernel<<<dim3(8, 256), 256, 0, stream>>>(hid_h, w2_h, cnt, tok, wtl, out);
}